// Round 8
// baseline (2258.299 us; speedup 1.0000x reference)
//
#include <hip/hip_runtime.h>

#define N_NODES 50000
#define N_EDGES 10000
#define N_INC   800000
// IN_F=64, HID=64, concat width 128.
// Input dtype (f32 vs raw-bf16) is DETECTED on device; see k_detect.

__device__ float bf2f(unsigned short u){
    return __uint_as_float(((unsigned)u) << 16);
}
__device__ unsigned short f2bf(float f){
    unsigned u = __float_as_uint(f);
    unsigned r = u + 0x7FFFu + ((u >> 16) & 1u);   // round-to-nearest-even
    return (unsigned short)(r >> 16);
}
// flag-branched load: bf=1 -> raw bf16 u16 stream, bf=0 -> float32
__device__ float ldv(const void* p, int i, int bf){
    if (bf) return bf2f(((const unsigned short*)p)[i]);
    return ((const float*)p)[i];
}

// dtype detection: hyperedge_weight ~ U[0.1,1.1]. If the buffer is raw bf16,
// ALL u16s decode into (0.05,1.2). If it is f32, even u16s are mantissa bits
// -> wild decoded magnitudes. NaN-safe (comparison false => f32 verdict).
__global__ void k_detect(const unsigned short* hw, int* flag){
    if (blockIdx.x == 0 && threadIdx.x == 0){
        int ok = 1;
        for (int j = 0; j < 64; ++j){
            float v = bf2f(hw[j]);
            if (!(v > 0.05f && v < 1.2f)) ok = 0;
        }
        *flag = ok;
    }
}

// sentinel beacon: final kernel overwrites every element
__global__ void k_sent(unsigned short* p, int n){
    int i = blockIdx.x*256 + threadIdx.x;
    if (i < n) p[i] = 0x4204;   // bf16 +33 / f32-pair ~33.06
}

__global__ void k_zero(float* p, int n){
    int i = blockIdx.x*256 + threadIdx.x;
    if (i < n) p[i] = 0.f;
}

__global__ void k_count(const int* nidx, const int* eidx, const void* hw,
                        float* D, int* Bc, const int* flag){
    int bf = *flag;
    int i = blockIdx.x*256 + threadIdx.x;
    if (i < N_INC){
        atomicAdd(&D[nidx[i]], ldv(hw, eidx[i], bf));
        atomicAdd(&Bc[eidx[i]], 1);
    }
}

__global__ void k_invert(float* D, const int* Bc, float* Binv){
    int i = blockIdx.x*256 + threadIdx.x;
    if (i < N_NODES) D[i] = D[i] > 0.f ? 1.f/D[i] : 0.f;      // becomes Dinv
    if (i < N_EDGES) Binv[i] = Bc[i] > 0 ? 1.f/(float)Bc[i] : 0.f;
}

// gate GEMM: X1[n,col] = [x|state](n,:) @ gate_W(:,col)
__global__ void k_gemm_gate(const void* x, const void* st, const void* W,
                            float* X1, const int* flag){
    int bf = *flag;
    int t = blockIdx.x*256 + threadIdx.x;
    if (t >= N_NODES*128) return;
    int n = t >> 7, col = t & 127;
    float acc = 0.f;
    for (int k = 0; k < 64; ++k)
        acc += ldv(x, n*64 + k, bf) * ldv(W, k*128 + col, bf);
    for (int k = 0; k < 64; ++k)
        acc += ldv(st, n*64 + k, bf) * ldv(W, (64+k)*128 + col, bf);
    X1[t] = acc;
}

// cand GEMM: cols 0-63 = cand_in @ cand_W, cols 64-127 = cand_in @ cand_res_W
// cand_in = [x | rs], rs internal f32
__global__ void k_gemm_cand(const void* x, const float* rs, const void* Wc,
                            const void* Wr, float* X1, const int* flag){
    int bf = *flag;
    int t = blockIdx.x*256 + threadIdx.x;
    if (t >= N_NODES*128) return;
    int n = t >> 7, col = t & 127;
    const void* W = (col < 64) ? Wc : Wr;
    int c = col & 63;
    float acc = 0.f;
    for (int k = 0; k < 64; ++k)
        acc += ldv(x, n*64 + k, bf) * ldv(W, k*64 + c, bf);
    for (int k = 0; k < 64; ++k)
        acc += rs[n*64 + k] * ldv(W, (64+k)*64 + c, bf);
    X1[t] = acc;
}

// edge aggregation: m[e,c] += X1[n,c]
__global__ void k_scat_e(const int* nidx, const int* eidx, const float* X1,
                         float* m, int C){
    int t = blockIdx.x*256 + threadIdx.x;
    if (t >= N_INC*C) return;
    int ii = t / C, c = t - ii*C;
    atomicAdd(&m[eidx[ii]*C + c], X1[nidx[ii]*128 + c]);
}

// node aggregation: h[n,c] += hw[e]*Binv[e]*m[e,c]
__global__ void k_scat_n(const int* nidx, const int* eidx, const void* hw,
                         const float* Binv, const float* m, float* h, int C,
                         const int* flag){
    int bf = *flag;
    int t = blockIdx.x*256 + threadIdx.x;
    if (t >= N_INC*C) return;
    int ii = t / C, c = t - ii*C;
    int e = eidx[ii];
    atomicAdd(&h[nidx[ii]*C + c], ldv(hw, e, bf) * Binv[e] * m[e*C + c]);
}

// gate finalize: relu -> LN(128) -> sigmoid -> zbuf, rs
__global__ void k_gate_fin(const void* x, const void* st, const float* Dinv,
                           const float* h, const void* gb, const void* lng,
                           const void* lnb, float* zbuf, float* rs,
                           const int* flag){
    int bf = *flag;
    int n = blockIdx.x*256 + threadIdx.x;
    if (n >= N_NODES) return;
    float di = Dinv[n];
    float sum = 0.f;
    for (int c = 0; c < 128; ++c){
        float base = (c < 64) ? ldv(x, n*64 + c, bf) : ldv(st, n*64 + c - 64, bf);
        float v = base + di*h[n*128 + c] + ldv(gb, c, bf);
        if (v < 0.f) v = 0.f;
        sum += v;
    }
    float mu = sum * (1.f/128.f);
    float vs = 0.f;
    for (int c = 0; c < 128; ++c){
        float base = (c < 64) ? ldv(x, n*64 + c, bf) : ldv(st, n*64 + c - 64, bf);
        float v = base + di*h[n*128 + c] + ldv(gb, c, bf);
        if (v < 0.f) v = 0.f;
        float d = v - mu;
        vs += d*d;
    }
    float inv = 1.f / sqrtf(vs*(1.f/128.f) + 1e-5f);
    for (int c = 0; c < 64; ++c){
        float s1 = ldv(st, n*64 + c, bf);
        float v0 = ldv(x, n*64 + c, bf) + di*h[n*128 + c]      + ldv(gb, c, bf);
        float v1 = s1                   + di*h[n*128 + 64 + c] + ldv(gb, 64 + c, bf);
        if (v0 < 0.f) v0 = 0.f;
        if (v1 < 0.f) v1 = 0.f;
        float u0 = (v0 - mu)*inv*ldv(lng, c, bf)      + ldv(lnb, c, bf);
        float u1 = (v1 - mu)*inv*ldv(lng, 64 + c, bf) + ldv(lnb, 64 + c, bf);
        float z = 1.f/(1.f + expf(-u0));
        float r = 1.f/(1.f + expf(-u1));
        zbuf[n*64 + c] = z;
        rs[n*64 + c] = r * s1;
    }
}

// cand finalize: relu -> LN(64) -> tanh -> GRU blend -> out (per-flag dtype)
__global__ void k_cand_fin(const void* st, const float* Dinv, const float* h,
                           const float* X1, const void* cb, const void* crb,
                           const void* lng, const void* lnb, const float* zbuf,
                           void* out, const int* flag){
    int bf = *flag;
    int n = blockIdx.x*256 + threadIdx.x;
    if (n >= N_NODES) return;
    float di = Dinv[n];
    float sum = 0.f;
    for (int c = 0; c < 64; ++c){
        float v = X1[n*128 + 64 + c] + ldv(crb, c, bf)
                + di*h[n*64 + c] + ldv(cb, c, bf);
        if (v < 0.f) v = 0.f;
        sum += v;
    }
    float mu = sum * (1.f/64.f);
    float vs = 0.f;
    for (int c = 0; c < 64; ++c){
        float v = X1[n*128 + 64 + c] + ldv(crb, c, bf)
                + di*h[n*64 + c] + ldv(cb, c, bf);
        if (v < 0.f) v = 0.f;
        float d = v - mu;
        vs += d*d;
    }
    float inv = 1.f / sqrtf(vs*(1.f/64.f) + 1e-5f);
    for (int c = 0; c < 64; ++c){
        float v = X1[n*128 + 64 + c] + ldv(crb, c, bf)
                + di*h[n*64 + c] + ldv(cb, c, bf);
        if (v < 0.f) v = 0.f;
        float u = (v - mu)*inv*ldv(lng, c, bf) + ldv(lnb, c, bf);
        float hc = tanhf(u);
        float z = zbuf[n*64 + c];
        float s = ldv(st, n*64 + c, bf);
        float res = (1.f - z)*s + z*hc;
        if (bf) ((unsigned short*)out)[n*64 + c] = f2bf(res);
        else    ((float*)out)[n*64 + c] = res;
    }
}

extern "C" void kernel_launch(void* const* d_in, const int* in_sizes, int n_in,
                              void* d_out, int out_size, void* d_ws, size_t ws_size,
                              hipStream_t stream){
    const void* x      = d_in[0];
    const void* state  = d_in[1];
    const int*  hidx   = (const int*)d_in[2];
    const void* hw     = d_in[3];
    const void* gate_W = d_in[4];
    const void* gate_b = d_in[5];
    const void* glng   = d_in[6];
    const void* glnb   = d_in[7];
    const void* cand_W = d_in[8];
    const void* cand_b = d_in[9];
    const void* clng   = d_in[10];
    const void* clnb   = d_in[11];
    const void* crW    = d_in[12];
    const void* crb    = d_in[13];
    (void)in_sizes; (void)n_in; (void)ws_size;

    const int* nidx = hidx;
    const int* eidx = hidx + N_INC;

    // workspace layout (byte offsets, 256B-aligned, total ~82.2 MB)
    char* w = (char*)d_ws;
    int*   flag = (int*)  (w);                 // 4 B (+pad)
    float* D    = (float*)(w + 256);           // 50048 f
    int*   Bc   = (int*)  (w + 200448);        // 10048 i (contiguous with D)
    float* Binv = (float*)(w + 240640);        // 10048 f
    float* m    = (float*)(w + 280832);        // 10000*128 f
    float* h    = (float*)(w + 5400832);       // 50000*128 f
    float* X1   = (float*)(w + 31000832);      // 50000*128 f
    float* zbuf = (float*)(w + 56600832);      // 50000*64 f
    float* rs   = (float*)(w + 69400832);      // 50000*64 f -> ends 82200832

    // dtype detection + sentinel
    k_detect<<<1, 64, 0, stream>>>((const unsigned short*)hw, flag);
    k_sent<<<(out_size + 255)/256, 256, 0, stream>>>((unsigned short*)d_out, out_size);

    // zero D+Bc (contiguous 60096 words), m, h
    k_zero<<<(60096 + 255)/256, 256, 0, stream>>>(D, 60096);
    k_zero<<<(N_EDGES*128 + 255)/256, 256, 0, stream>>>(m, N_EDGES*128);
    k_zero<<<(N_NODES*128 + 255)/256, 256, 0, stream>>>(h, N_NODES*128);

    // degrees
    k_count<<<(N_INC + 255)/256, 256, 0, stream>>>(nidx, eidx, hw, D, Bc, flag);
    k_invert<<<(N_NODES + 255)/256, 256, 0, stream>>>(D, Bc, Binv);

    // ---- gate path ----
    k_gemm_gate<<<(N_NODES*128 + 255)/256, 256, 0, stream>>>(x, state, gate_W, X1, flag);
    k_scat_e<<<(N_INC*128 + 255)/256, 256, 0, stream>>>(nidx, eidx, X1, m, 128);
    k_scat_n<<<(N_INC*128 + 255)/256, 256, 0, stream>>>(nidx, eidx, hw, Binv, m, h, 128, flag);
    k_gate_fin<<<(N_NODES + 255)/256, 256, 0, stream>>>(x, state, D, h, gate_b, glng, glnb,
                                                        zbuf, rs, flag);

    // ---- candidate path ----
    k_gemm_cand<<<(N_NODES*128 + 255)/256, 256, 0, stream>>>(x, rs, cand_W, crW, X1, flag);
    k_zero<<<(N_EDGES*64 + 255)/256, 256, 0, stream>>>(m, N_EDGES*64);
    k_zero<<<(N_NODES*64 + 255)/256, 256, 0, stream>>>(h, N_NODES*64);
    k_scat_e<<<(N_INC*64 + 255)/256, 256, 0, stream>>>(nidx, eidx, X1, m, 64);
    k_scat_n<<<(N_INC*64 + 255)/256, 256, 0, stream>>>(nidx, eidx, hw, Binv, m, h, 64, flag);
    k_cand_fin<<<(N_NODES + 255)/256, 256, 0, stream>>>(state, D, h, X1, cand_b, crb,
                                                        clng, clnb, zbuf, d_out, flag);
}

// Round 9
// 1892.421 us; speedup vs baseline: 1.1933x; 1.1933x over previous
//
#include <hip/hip_runtime.h>

#define N_NODES 50000
#define N_EDGES 10000
#define N_INC   800000
// IN_F=64, HID=64, concat width 128.
// Input dtype (f32 vs raw-bf16) detected on device (k_detect) — f32 confirmed in R8.

__device__ float bf2f(unsigned short u){
    return __uint_as_float(((unsigned)u) << 16);
}
__device__ unsigned short f2bf(float f){
    unsigned u = __float_as_uint(f);
    unsigned r = u + 0x7FFFu + ((u >> 16) & 1u);
    return (unsigned short)(r >> 16);
}
__device__ float ldv(const void* p, int i, int bf){
    if (bf) return bf2f(((const unsigned short*)p)[i]);
    return ((const float*)p)[i];
}

__global__ void k_detect(const unsigned short* hw, int* flag){
    if (blockIdx.x == 0 && threadIdx.x == 0){
        int ok = 1;
        for (int j = 0; j < 64; ++j){
            float v = bf2f(hw[j]);
            if (!(v > 0.05f && v < 1.2f)) ok = 0;
        }
        *flag = ok;
    }
}

__global__ void k_sent(unsigned short* p, int n){
    int i = blockIdx.x*256 + threadIdx.x;
    if (i < n) p[i] = 0x4204;
}

__global__ void k_zero(float* p, int n){
    int i = blockIdx.x*256 + threadIdx.x;
    if (i < n) p[i] = 0.f;
}

// counts: weighted node degree D, node degree Dc, edge cardinality Bc
__global__ void k_count(const int* nidx, const int* eidx, const void* hw,
                        float* D, int* Dc, int* Bc, const int* flag){
    int bf = *flag;
    int i = blockIdx.x*256 + threadIdx.x;
    if (i < N_INC){
        atomicAdd(&D[nidx[i]], ldv(hw, eidx[i], bf));
        atomicAdd(&Dc[nidx[i]], 1);
        atomicAdd(&Bc[eidx[i]], 1);
    }
}

__global__ void k_invert(float* D, const int* Bc, float* Binv){
    int i = blockIdx.x*256 + threadIdx.x;
    if (i < N_NODES) D[i] = D[i] > 0.f ? 1.f/D[i] : 0.f;      // becomes Dinv
    if (i < N_EDGES) Binv[i] = Bc[i] > 0 ? 1.f/(float)Bc[i] : 0.f;
}

// ---- chunked exclusive scan, no LDS: chunk sums -> serial chunk scan -> fill ----
__global__ void k_chunksum(const int* cnt, int* csum, int n, int nchunks){
    int ch = blockIdx.x*256 + threadIdx.x;
    if (ch >= nchunks) return;
    int beg = ch*128, end = beg + 128;
    if (end > n) end = n;
    int s = 0;
    for (int i = beg; i < end; ++i) s += cnt[i];
    csum[ch] = s;
}
__global__ void k_chunkscan(const int* csum, int* cbase, int nchunks){
    if (blockIdx.x == 0 && threadIdx.x == 0){
        int run = 0;
        for (int ch = 0; ch < nchunks; ++ch){
            cbase[ch] = run;
            run += csum[ch];
        }
    }
}
__global__ void k_chunkfill(const int* cnt, const int* cbase, int* indptr,
                            int* cursor, int n, int nchunks){
    int ch = blockIdx.x*256 + threadIdx.x;
    if (ch >= nchunks) return;
    int beg = ch*128, end = beg + 128;
    if (end > n) end = n;
    int run = cbase[ch];
    for (int i = beg; i < end; ++i){
        indptr[i] = run;
        cursor[i] = run;
        run += cnt[i];
    }
}

// fill both CSR adjacency lists
__global__ void k_fill(const int* nidx, const int* eidx,
                       int* cursor_n, int* nlist,
                       int* cursor_e, int* elist){
    int i = blockIdx.x*256 + threadIdx.x;
    if (i < N_INC){
        int pn = atomicAdd(&cursor_n[nidx[i]], 1);
        nlist[pn] = eidx[i];
        int pe = atomicAdd(&cursor_e[eidx[i]], 1);
        elist[pe] = nidx[i];
    }
}

// gate GEMM: X1[n,col] = [x|state](n,:) @ gate_W(:,col)
__global__ void k_gemm_gate(const void* x, const void* st, const void* W,
                            float* X1, const int* flag){
    int bf = *flag;
    int t = blockIdx.x*256 + threadIdx.x;
    if (t >= N_NODES*128) return;
    int n = t >> 7, col = t & 127;
    float acc = 0.f;
    for (int k = 0; k < 64; ++k)
        acc += ldv(x, n*64 + k, bf) * ldv(W, k*128 + col, bf);
    for (int k = 0; k < 64; ++k)
        acc += ldv(st, n*64 + k, bf) * ldv(W, (64+k)*128 + col, bf);
    X1[t] = acc;
}

// cand GEMM: cols 0-63 = cand_in @ cand_W, 64-127 = cand_in @ cand_res_W
__global__ void k_gemm_cand(const void* x, const float* rs, const void* Wc,
                            const void* Wr, float* X1, const int* flag){
    int bf = *flag;
    int t = blockIdx.x*256 + threadIdx.x;
    if (t >= N_NODES*128) return;
    int n = t >> 7, col = t & 127;
    const void* W = (col < 64) ? Wc : Wr;
    int c = col & 63;
    float acc = 0.f;
    for (int k = 0; k < 64; ++k)
        acc += ldv(x, n*64 + k, bf) * ldv(W, k*64 + c, bf);
    for (int k = 0; k < 64; ++k)
        acc += rs[n*64 + k] * ldv(W, (64+k)*64 + c, bf);
    X1[t] = acc;
}

// edge gather: m[e,c] = hw[e]*Binv[e] * sum_{n in e} X1[n,c]   (X1 ld = 128)
__global__ void k_gather_e(const int* indptr_e, const int* Bc, const int* elist,
                           const float* X1, const void* hw, const float* Binv,
                           float* m, int C, const int* flag){
    int bf = *flag;
    int t = blockIdx.x*256 + threadIdx.x;
    if (t >= N_EDGES*C) return;
    int e = t / C, c = t - e*C;
    int beg = indptr_e[e], cnt = Bc[e];
    float acc = 0.f;
    for (int j = 0; j < cnt; ++j){
        int n = elist[beg + j];
        acc += X1[n*128 + c];
    }
    m[e*C + c] = acc * ldv(hw, e, bf) * Binv[e];
}

// node gather: h[n,c] = sum_{e in N(n)} m[e,c]
__global__ void k_gather_n(const int* indptr_n, const int* Dc, const int* nlist,
                           const float* m, float* h, int C){
    int t = blockIdx.x*256 + threadIdx.x;
    if (t >= N_NODES*C) return;
    int n = t / C, c = t - n*C;
    int beg = indptr_n[n], cnt = Dc[n];
    float acc = 0.f;
    for (int j = 0; j < cnt; ++j){
        int e = nlist[beg + j];
        acc += m[e*C + c];
    }
    h[n*C + c] = acc;
}

// gate finalize: relu -> LN(128) -> sigmoid -> zbuf, rs
__global__ void k_gate_fin(const void* x, const void* st, const float* Dinv,
                           const float* h, const void* gb, const void* lng,
                           const void* lnb, float* zbuf, float* rs,
                           const int* flag){
    int bf = *flag;
    int n = blockIdx.x*256 + threadIdx.x;
    if (n >= N_NODES) return;
    float di = Dinv[n];
    float sum = 0.f;
    for (int c = 0; c < 128; ++c){
        float base = (c < 64) ? ldv(x, n*64 + c, bf) : ldv(st, n*64 + c - 64, bf);
        float v = base + di*h[n*128 + c] + ldv(gb, c, bf);
        if (v < 0.f) v = 0.f;
        sum += v;
    }
    float mu = sum * (1.f/128.f);
    float vs = 0.f;
    for (int c = 0; c < 128; ++c){
        float base = (c < 64) ? ldv(x, n*64 + c, bf) : ldv(st, n*64 + c - 64, bf);
        float v = base + di*h[n*128 + c] + ldv(gb, c, bf);
        if (v < 0.f) v = 0.f;
        float d = v - mu;
        vs += d*d;
    }
    float inv = 1.f / sqrtf(vs*(1.f/128.f) + 1e-5f);
    for (int c = 0; c < 64; ++c){
        float s1 = ldv(st, n*64 + c, bf);
        float v0 = ldv(x, n*64 + c, bf) + di*h[n*128 + c]      + ldv(gb, c, bf);
        float v1 = s1                   + di*h[n*128 + 64 + c] + ldv(gb, 64 + c, bf);
        if (v0 < 0.f) v0 = 0.f;
        if (v1 < 0.f) v1 = 0.f;
        float u0 = (v0 - mu)*inv*ldv(lng, c, bf)      + ldv(lnb, c, bf);
        float u1 = (v1 - mu)*inv*ldv(lng, 64 + c, bf) + ldv(lnb, 64 + c, bf);
        float z = 1.f/(1.f + expf(-u0));
        float r = 1.f/(1.f + expf(-u1));
        zbuf[n*64 + c] = z;
        rs[n*64 + c] = r * s1;
    }
}

// cand finalize: relu -> LN(64) -> tanh -> GRU blend -> out
__global__ void k_cand_fin(const void* st, const float* Dinv, const float* h,
                           const float* X1, const void* cb, const void* crb,
                           const void* lng, const void* lnb, const float* zbuf,
                           void* out, const int* flag){
    int bf = *flag;
    int n = blockIdx.x*256 + threadIdx.x;
    if (n >= N_NODES) return;
    float di = Dinv[n];
    float sum = 0.f;
    for (int c = 0; c < 64; ++c){
        float v = X1[n*128 + 64 + c] + ldv(crb, c, bf)
                + di*h[n*64 + c] + ldv(cb, c, bf);
        if (v < 0.f) v = 0.f;
        sum += v;
    }
    float mu = sum * (1.f/64.f);
    float vs = 0.f;
    for (int c = 0; c < 64; ++c){
        float v = X1[n*128 + 64 + c] + ldv(crb, c, bf)
                + di*h[n*64 + c] + ldv(cb, c, bf);
        if (v < 0.f) v = 0.f;
        float d = v - mu;
        vs += d*d;
    }
    float inv = 1.f / sqrtf(vs*(1.f/64.f) + 1e-5f);
    for (int c = 0; c < 64; ++c){
        float v = X1[n*128 + 64 + c] + ldv(crb, c, bf)
                + di*h[n*64 + c] + ldv(cb, c, bf);
        if (v < 0.f) v = 0.f;
        float u = (v - mu)*inv*ldv(lng, c, bf) + ldv(lnb, c, bf);
        float hc = tanhf(u);
        float z = zbuf[n*64 + c];
        float s = ldv(st, n*64 + c, bf);
        float res = (1.f - z)*s + z*hc;
        if (bf) ((unsigned short*)out)[n*64 + c] = f2bf(res);
        else    ((float*)out)[n*64 + c] = res;
    }
}

extern "C" void kernel_launch(void* const* d_in, const int* in_sizes, int n_in,
                              void* d_out, int out_size, void* d_ws, size_t ws_size,
                              hipStream_t stream){
    const void* x      = d_in[0];
    const void* state  = d_in[1];
    const int*  hidx   = (const int*)d_in[2];
    const void* hw     = d_in[3];
    const void* gate_W = d_in[4];
    const void* gate_b = d_in[5];
    const void* glng   = d_in[6];
    const void* glnb   = d_in[7];
    const void* cand_W = d_in[8];
    const void* cand_b = d_in[9];
    const void* clng   = d_in[10];
    const void* clnb   = d_in[11];
    const void* crW    = d_in[12];
    const void* crb    = d_in[13];
    (void)in_sizes; (void)n_in; (void)ws_size;

    const int* nidx = hidx;
    const int* eidx = hidx + N_INC;

    const int NCH_N = (N_NODES + 127)/128;   // 391
    const int NCH_E = (N_EDGES + 127)/128;   // 79

    // ---- workspace (byte offsets, 256B-aligned, total ~76.5 MB; 82.2 MB proven OK) ----
    char* w = (char*)d_ws;
    int*   flag     = (int*)  (w);
    float* D        = (float*)(w + 256);        // 50048 f  (-> Dinv)
    int*   Bc       = (int*)  (w + 200448);     // 10048 i
    int*   Dc       = (int*)  (w + 240640);     // 50048 i   (D,Bc,Dc contiguous: zeroed)
    float* Binv     = (float*)(w + 440832);     // 10048 f
    int*   indptr_n = (int*)  (w + 481024);     // 50048 i
    int*   cursor_n = (int*)  (w + 681216);     // 50048 i
    int*   indptr_e = (int*)  (w + 881408);     // 10048 i
    int*   cursor_e = (int*)  (w + 921600);     // 10048 i
    int*   csum_n   = (int*)  (w + 961792);     // 512 i
    int*   cbase_n  = (int*)  (w + 963840);     // 512 i
    int*   csum_e   = (int*)  (w + 965888);     // 256 i
    int*   cbase_e  = (int*)  (w + 966912);     // 256 i
    int*   nlist    = (int*)  (w + 967936);     // 800000 i
    int*   elist    = (int*)  (w + 4167936);    // 800000 i
    float* m        = (float*)(w + 7367936);    // 10000*128 f
    float* X1h      = (float*)(w + 12487936);   // 50000*128 f  (X1, aliased as gate h)
    float* h2       = (float*)(w + 38087936);   // 50000*64 f   (cand h)
    float* zbuf     = (float*)(w + 50887936);   // 50000*64 f
    float* rs       = (float*)(w + 63687936);   // 50000*64 f -> ends 76487936

    // dtype detect + sentinel
    k_detect<<<1, 64, 0, stream>>>((const unsigned short*)hw, flag);
    k_sent<<<(out_size + 255)/256, 256, 0, stream>>>((unsigned short*)d_out, out_size);

    // zero D,Bc,Dc (contiguous 110144 words)
    k_zero<<<(110144 + 255)/256, 256, 0, stream>>>(D, 110144);

    // degrees + CSR build
    k_count<<<(N_INC + 255)/256, 256, 0, stream>>>(nidx, eidx, hw, D, Dc, Bc, flag);
    k_invert<<<(N_NODES + 255)/256, 256, 0, stream>>>(D, Bc, Binv);
    k_chunksum<<<(NCH_N + 255)/256, 256, 0, stream>>>(Dc, csum_n, N_NODES, NCH_N);
    k_chunkscan<<<1, 64, 0, stream>>>(csum_n, cbase_n, NCH_N);
    k_chunkfill<<<(NCH_N + 255)/256, 256, 0, stream>>>(Dc, cbase_n, indptr_n, cursor_n,
                                                       N_NODES, NCH_N);
    k_chunksum<<<(NCH_E + 255)/256, 256, 0, stream>>>(Bc, csum_e, N_EDGES, NCH_E);
    k_chunkscan<<<1, 64, 0, stream>>>(csum_e, cbase_e, NCH_E);
    k_chunkfill<<<(NCH_E + 255)/256, 256, 0, stream>>>(Bc, cbase_e, indptr_e, cursor_e,
                                                       N_EDGES, NCH_E);
    k_fill<<<(N_INC + 255)/256, 256, 0, stream>>>(nidx, eidx, cursor_n, nlist,
                                                  cursor_e, elist);

    // ---- gate path ----
    k_gemm_gate<<<(N_NODES*128 + 255)/256, 256, 0, stream>>>(x, state, gate_W, X1h, flag);
    k_gather_e<<<(N_EDGES*128 + 255)/256, 256, 0, stream>>>(indptr_e, Bc, elist, X1h,
                                                            hw, Binv, m, 128, flag);
    k_gather_n<<<(N_NODES*128 + 255)/256, 256, 0, stream>>>(indptr_n, Dc, nlist, m,
                                                            X1h, 128);   // X1 dead -> h
    k_gate_fin<<<(N_NODES + 255)/256, 256, 0, stream>>>(x, state, D, X1h, gate_b,
                                                        glng, glnb, zbuf, rs, flag);

    // ---- candidate path ----
    k_gemm_cand<<<(N_NODES*128 + 255)/256, 256, 0, stream>>>(x, rs, cand_W, crW, X1h, flag);
    k_gather_e<<<(N_EDGES*64 + 255)/256, 256, 0, stream>>>(indptr_e, Bc, elist, X1h,
                                                           hw, Binv, m, 64, flag);
    k_gather_n<<<(N_NODES*64 + 255)/256, 256, 0, stream>>>(indptr_n, Dc, nlist, m,
                                                           h2, 64);
    k_cand_fin<<<(N_NODES + 255)/256, 256, 0, stream>>>(state, D, h2, X1h, cand_b, crb,
                                                        clng, clnb, zbuf, d_out, flag);
}

// Round 10
// 1550.147 us; speedup vs baseline: 1.4568x; 1.2208x over previous
//
#include <hip/hip_runtime.h>

#define N_NODES 50000
#define N_EDGES 10000
#define N_INC   800000
// IN_F=64, HID=64, concat width 128.
// Input dtype (f32 vs raw-bf16) detected on device (k_detect) — f32 confirmed in R8.

__device__ float bf2f(unsigned short u){
    return __uint_as_float(((unsigned)u) << 16);
}
__device__ unsigned short f2bf(float f){
    unsigned u = __float_as_uint(f);
    unsigned r = u + 0x7FFFu + ((u >> 16) & 1u);
    return (unsigned short)(r >> 16);
}
__device__ float ldv(const void* p, int i, int bf){
    if (bf) return bf2f(((const unsigned short*)p)[i]);
    return ((const float*)p)[i];
}

__global__ void k_detect(const unsigned short* hw, int* flag){
    if (blockIdx.x == 0 && threadIdx.x == 0){
        int ok = 1;
        for (int j = 0; j < 64; ++j){
            float v = bf2f(hw[j]);
            if (!(v > 0.05f && v < 1.2f)) ok = 0;
        }
        *flag = ok;
    }
}

__global__ void k_sent(unsigned short* p, int n){
    int i = blockIdx.x*256 + threadIdx.x;
    if (i < n) p[i] = 0x4204;
}

__global__ void k_zero(float* p, int n){
    int i = blockIdx.x*256 + threadIdx.x;
    if (i < n) p[i] = 0.f;
}

// counts: weighted node degree D, node degree Dc, edge cardinality Bc
__global__ void k_count(const int* nidx, const int* eidx, const void* hw,
                        float* D, int* Dc, int* Bc, const int* flag){
    int bf = *flag;
    int i = blockIdx.x*256 + threadIdx.x;
    if (i < N_INC){
        atomicAdd(&D[nidx[i]], ldv(hw, eidx[i], bf));
        atomicAdd(&Dc[nidx[i]], 1);
        atomicAdd(&Bc[eidx[i]], 1);
    }
}

__global__ void k_invert(float* D, const int* Bc, float* Binv){
    int i = blockIdx.x*256 + threadIdx.x;
    if (i < N_NODES) D[i] = D[i] > 0.f ? 1.f/D[i] : 0.f;      // becomes Dinv
    if (i < N_EDGES) Binv[i] = Bc[i] > 0 ? 1.f/(float)Bc[i] : 0.f;
}

// ---- chunked exclusive scan, no LDS ----
__global__ void k_chunksum(const int* cnt, int* csum, int n, int nchunks){
    int ch = blockIdx.x*256 + threadIdx.x;
    if (ch >= nchunks) return;
    int beg = ch*128, end = beg + 128;
    if (end > n) end = n;
    int s = 0;
    for (int i = beg; i < end; ++i) s += cnt[i];
    csum[ch] = s;
}
__global__ void k_chunkscan(const int* csum, int* cbase, int nchunks){
    if (blockIdx.x == 0 && threadIdx.x == 0){
        int run = 0;
        for (int ch = 0; ch < nchunks; ++ch){
            cbase[ch] = run;
            run += csum[ch];
        }
    }
}
__global__ void k_chunkfill(const int* cnt, const int* cbase, int* indptr,
                            int* cursor, int n, int nchunks){
    int ch = blockIdx.x*256 + threadIdx.x;
    if (ch >= nchunks) return;
    int beg = ch*128, end = beg + 128;
    if (end > n) end = n;
    int run = cbase[ch];
    for (int i = beg; i < end; ++i){
        indptr[i] = run;
        cursor[i] = run;
        run += cnt[i];
    }
}

__global__ void k_fill(const int* nidx, const int* eidx,
                       int* cursor_n, int* nlist,
                       int* cursor_e, int* elist){
    int i = blockIdx.x*256 + threadIdx.x;
    if (i < N_INC){
        int pn = atomicAdd(&cursor_n[nidx[i]], 1);
        nlist[pn] = eidx[i];
        int pe = atomicAdd(&cursor_e[eidx[i]], 1);
        elist[pe] = nidx[i];
    }
}

// gate GEMM: X1[n,col] = [x|state](n,:) @ gate_W(:,col)
__global__ void k_gemm_gate(const void* x, const void* st, const void* W,
                            float* X1, const int* flag){
    int bf = *flag;
    int t = blockIdx.x*256 + threadIdx.x;
    if (t >= N_NODES*128) return;
    int n = t >> 7, col = t & 127;
    float acc = 0.f;
    for (int k = 0; k < 64; ++k)
        acc += ldv(x, n*64 + k, bf) * ldv(W, k*128 + col, bf);
    for (int k = 0; k < 64; ++k)
        acc += ldv(st, n*64 + k, bf) * ldv(W, (64+k)*128 + col, bf);
    X1[t] = acc;
}

// cand GEMM: cols 0-63 = cand_in @ cand_W, 64-127 = cand_in @ cand_res_W
__global__ void k_gemm_cand(const void* x, const float* rs, const void* Wc,
                            const void* Wr, float* X1, const int* flag){
    int bf = *flag;
    int t = blockIdx.x*256 + threadIdx.x;
    if (t >= N_NODES*128) return;
    int n = t >> 7, col = t & 127;
    const void* W = (col < 64) ? Wc : Wr;
    int c = col & 63;
    float acc = 0.f;
    for (int k = 0; k < 64; ++k)
        acc += ldv(x, n*64 + k, bf) * ldv(W, k*64 + c, bf);
    for (int k = 0; k < 64; ++k)
        acc += rs[n*64 + k] * ldv(W, (64+k)*64 + c, bf);
    X1[t] = acc;
}

// edge gather: m[e,c] = hw[e]*Binv[e] * sum_{n in e} X1[n,c]   (X1 ld = 128)
__global__ void k_gather_e(const int* indptr_e, const int* Bc, const int* elist,
                           const float* X1, const void* hw, const float* Binv,
                           float* m, int C, const int* flag){
    int bf = *flag;
    int t = blockIdx.x*256 + threadIdx.x;
    if (t >= N_EDGES*C) return;
    int e = t / C, c = t - e*C;
    int beg = indptr_e[e], cnt = Bc[e];
    float acc = 0.f;
    for (int j = 0; j < cnt; ++j){
        int n = elist[beg + j];
        acc += X1[n*128 + c];
    }
    m[e*C + c] = acc * ldv(hw, e, bf) * Binv[e];
}

// node gather: h[n,c] = sum_{e in N(n)} m[e,c]
__global__ void k_gather_n(const int* indptr_n, const int* Dc, const int* nlist,
                           const float* m, float* h, int C){
    int t = blockIdx.x*256 + threadIdx.x;
    if (t >= N_NODES*C) return;
    int n = t / C, c = t - n*C;
    int beg = indptr_n[n], cnt = Dc[n];
    float acc = 0.f;
    for (int j = 0; j < cnt; ++j){
        int e = nlist[beg + j];
        acc += m[e*C + c];
    }
    h[n*C + c] = acc;
}

// gate prep: thread per (node, 64-col half). Coalesced 256B/lane reads.
// v = relu(base + Dinv*h + gb) written in place over h; per-half sum/sumsq partials.
__global__ void k_prep_gate(const void* x, const void* st, const float* Dinv,
                            float* h, const void* gb, float* pstat,
                            const int* flag){
    int bf = *flag;
    int t = blockIdx.x*256 + threadIdx.x;
    if (t >= N_NODES*2) return;
    int n = t >> 1, half = t & 1;
    float di = Dinv[n];
    float s = 0.f, sq = 0.f;
    for (int j = 0; j < 64; ++j){
        int c = half*64 + j;
        float base = (half == 0) ? ldv(x, n*64 + j, bf) : ldv(st, n*64 + j, bf);
        float v = base + di*h[n*128 + c] + ldv(gb, c, bf);
        if (v < 0.f) v = 0.f;
        h[n*128 + c] = v;
        s += v; sq += v*v;
    }
    pstat[t*2]     = s;
    pstat[t*2 + 1] = sq;
}

// gate fin: thread per (node, col<64). All reads coalesced / wave-broadcast.
__global__ void k_gate_fin2(const void* st, const float* P, const float* pstat,
                            const void* lng, const void* lnb,
                            float* zbuf, float* rs, const int* flag){
    int bf = *flag;
    int t = blockIdx.x*256 + threadIdx.x;
    if (t >= N_NODES*64) return;
    int n = t >> 6, c = t & 63;
    float s  = pstat[4*n]     + pstat[4*n + 2];
    float sq = pstat[4*n + 1] + pstat[4*n + 3];
    float mu = s * (1.f/128.f);
    float var = sq * (1.f/128.f) - mu*mu;
    if (var < 0.f) var = 0.f;
    float inv = 1.f / sqrtf(var + 1e-5f);
    float v0 = P[n*128 + c];
    float v1 = P[n*128 + 64 + c];
    float u0 = (v0 - mu)*inv*ldv(lng, c, bf)      + ldv(lnb, c, bf);
    float u1 = (v1 - mu)*inv*ldv(lng, 64 + c, bf) + ldv(lnb, 64 + c, bf);
    float z = 1.f/(1.f + expf(-u0));
    float r = 1.f/(1.f + expf(-u1));
    float s1 = ldv(st, t, bf);
    zbuf[t] = z;
    rs[t]   = r * s1;
}

// cand prep: thread per node (64 cols, 256B/lane). v in place over h2 + stats.
__global__ void k_prep_cand(const float* X1, const float* Dinv, float* h2,
                            const void* cbv, const void* crb, float* pstat,
                            const int* flag){
    int bf = *flag;
    int n = blockIdx.x*256 + threadIdx.x;
    if (n >= N_NODES) return;
    float di = Dinv[n];
    float s = 0.f, sq = 0.f;
    for (int c = 0; c < 64; ++c){
        float v = X1[n*128 + 64 + c] + ldv(crb, c, bf)
                + di*h2[n*64 + c] + ldv(cbv, c, bf);
        if (v < 0.f) v = 0.f;
        h2[n*64 + c] = v;
        s += v; sq += v*v;
    }
    pstat[n*2]     = s;
    pstat[n*2 + 1] = sq;
}

// cand fin: thread per (node, col). LN + tanh + GRU blend -> out.
__global__ void k_cand_fin2(const void* st, const float* P2, const float* pstat,
                            const void* lng, const void* lnb, const float* zbuf,
                            void* out, const int* flag){
    int bf = *flag;
    int t = blockIdx.x*256 + threadIdx.x;
    if (t >= N_NODES*64) return;
    int n = t >> 6, c = t & 63;
    float s  = pstat[2*n];
    float sq = pstat[2*n + 1];
    float mu = s * (1.f/64.f);
    float var = sq * (1.f/64.f) - mu*mu;
    if (var < 0.f) var = 0.f;
    float inv = 1.f / sqrtf(var + 1e-5f);
    float v = P2[t];
    float u = (v - mu)*inv*ldv(lng, c, bf) + ldv(lnb, c, bf);
    float hc = tanhf(u);
    float z = zbuf[t];
    float sv = ldv(st, t, bf);
    float res = (1.f - z)*sv + z*hc;
    if (bf) ((unsigned short*)out)[t] = f2bf(res);
    else    ((float*)out)[t] = res;
}

extern "C" void kernel_launch(void* const* d_in, const int* in_sizes, int n_in,
                              void* d_out, int out_size, void* d_ws, size_t ws_size,
                              hipStream_t stream){
    const void* x      = d_in[0];
    const void* state  = d_in[1];
    const int*  hidx   = (const int*)d_in[2];
    const void* hw     = d_in[3];
    const void* gate_W = d_in[4];
    const void* gate_b = d_in[5];
    const void* glng   = d_in[6];
    const void* glnb   = d_in[7];
    const void* cand_W = d_in[8];
    const void* cand_b = d_in[9];
    const void* clng   = d_in[10];
    const void* clnb   = d_in[11];
    const void* crW    = d_in[12];
    const void* crb    = d_in[13];
    (void)in_sizes; (void)n_in; (void)ws_size;

    const int* nidx = hidx;
    const int* eidx = hidx + N_INC;

    const int NCH_N = (N_NODES + 127)/128;   // 391
    const int NCH_E = (N_EDGES + 127)/128;   // 79

    // ---- workspace (byte offsets, 256B-aligned, total ~77.7 MB; 82.2 MB proven OK) ----
    char* w = (char*)d_ws;
    int*   flag     = (int*)  (w);
    float* D        = (float*)(w + 256);        // 50048 f  (-> Dinv)
    int*   Bc       = (int*)  (w + 200448);     // 10048 i
    int*   Dc       = (int*)  (w + 240640);     // 50048 i   (D,Bc,Dc contiguous: zeroed)
    float* Binv     = (float*)(w + 440832);     // 10048 f
    int*   indptr_n = (int*)  (w + 481024);     // 50048 i
    int*   cursor_n = (int*)  (w + 681216);     // 50048 i
    int*   indptr_e = (int*)  (w + 881408);     // 10048 i
    int*   cursor_e = (int*)  (w + 921600);     // 10048 i
    int*   csum_n   = (int*)  (w + 961792);     // 512 i
    int*   cbase_n  = (int*)  (w + 963840);     // 512 i
    int*   csum_e   = (int*)  (w + 965888);     // 256 i
    int*   cbase_e  = (int*)  (w + 966912);     // 256 i
    int*   nlist    = (int*)  (w + 967936);     // 800000 i
    int*   elist    = (int*)  (w + 4167936);    // 800000 i
    float* m        = (float*)(w + 7367936);    // 10000*128 f
    float* X1h      = (float*)(w + 12487936);   // 50000*128 f  (X1 / gate h / gate P)
    float* h2       = (float*)(w + 38087936);   // 50000*64 f   (cand h / cand P)
    float* zbuf     = (float*)(w + 50887936);   // 50000*64 f
    float* rs       = (float*)(w + 63687936);   // 50000*64 f
    float* pstat_g  = (float*)(w + 76487936);   // 200000 f
    float* pstat_c  = (float*)(w + 77288704);   // 100000 f -> ends 77688704

    // dtype detect + sentinel
    k_detect<<<1, 64, 0, stream>>>((const unsigned short*)hw, flag);
    k_sent<<<(out_size + 255)/256, 256, 0, stream>>>((unsigned short*)d_out, out_size);

    // zero D,Bc,Dc (contiguous 110144 words)
    k_zero<<<(110144 + 255)/256, 256, 0, stream>>>(D, 110144);

    // degrees + CSR build
    k_count<<<(N_INC + 255)/256, 256, 0, stream>>>(nidx, eidx, hw, D, Dc, Bc, flag);
    k_invert<<<(N_NODES + 255)/256, 256, 0, stream>>>(D, Bc, Binv);
    k_chunksum<<<(NCH_N + 255)/256, 256, 0, stream>>>(Dc, csum_n, N_NODES, NCH_N);
    k_chunkscan<<<1, 64, 0, stream>>>(csum_n, cbase_n, NCH_N);
    k_chunkfill<<<(NCH_N + 255)/256, 256, 0, stream>>>(Dc, cbase_n, indptr_n, cursor_n,
                                                       N_NODES, NCH_N);
    k_chunksum<<<(NCH_E + 255)/256, 256, 0, stream>>>(Bc, csum_e, N_EDGES, NCH_E);
    k_chunkscan<<<1, 64, 0, stream>>>(csum_e, cbase_e, NCH_E);
    k_chunkfill<<<(NCH_E + 255)/256, 256, 0, stream>>>(Bc, cbase_e, indptr_e, cursor_e,
                                                       N_EDGES, NCH_E);
    k_fill<<<(N_INC + 255)/256, 256, 0, stream>>>(nidx, eidx, cursor_n, nlist,
                                                  cursor_e, elist);

    // ---- gate path ----
    k_gemm_gate<<<(N_NODES*128 + 255)/256, 256, 0, stream>>>(x, state, gate_W, X1h, flag);
    k_gather_e<<<(N_EDGES*128 + 255)/256, 256, 0, stream>>>(indptr_e, Bc, elist, X1h,
                                                            hw, Binv, m, 128, flag);
    k_gather_n<<<(N_NODES*128 + 255)/256, 256, 0, stream>>>(indptr_n, Dc, nlist, m,
                                                            X1h, 128);   // X1 dead -> h
    k_prep_gate<<<(N_NODES*2 + 255)/256, 256, 0, stream>>>(x, state, D, X1h, gate_b,
                                                           pstat_g, flag);
    k_gate_fin2<<<(N_NODES*64 + 255)/256, 256, 0, stream>>>(state, X1h, pstat_g,
                                                            glng, glnb, zbuf, rs, flag);

    // ---- candidate path ----
    k_gemm_cand<<<(N_NODES*128 + 255)/256, 256, 0, stream>>>(x, rs, cand_W, crW, X1h, flag);
    k_gather_e<<<(N_EDGES*64 + 255)/256, 256, 0, stream>>>(indptr_e, Bc, elist, X1h,
                                                           hw, Binv, m, 64, flag);
    k_gather_n<<<(N_NODES*64 + 255)/256, 256, 0, stream>>>(indptr_n, Dc, nlist, m,
                                                           h2, 64);
    k_prep_cand<<<(N_NODES + 255)/256, 256, 0, stream>>>(X1h, D, h2, cand_b, crb,
                                                         pstat_c, flag);
    k_cand_fin2<<<(N_NODES*64 + 255)/256, 256, 0, stream>>>(state, h2, pstat_c,
                                                            clng, clnb, zbuf,
                                                            d_out, flag);
}

// Round 11
// 1354.849 us; speedup vs baseline: 1.6668x; 1.1441x over previous
//
#include <hip/hip_runtime.h>

#define N_NODES 50000
#define N_EDGES 10000
#define N_INC   800000
// IN_F=64, HID=64, concat width 128.
// Input dtype (f32 vs raw-bf16) detected on device (k_detect) — f32 confirmed in R8.

__device__ float bf2f(unsigned short u){
    return __uint_as_float(((unsigned)u) << 16);
}
__device__ unsigned short f2bf(float f){
    unsigned u = __float_as_uint(f);
    unsigned r = u + 0x7FFFu + ((u >> 16) & 1u);
    return (unsigned short)(r >> 16);
}
__device__ float ldv(const void* p, int i, int bf){
    if (bf) return bf2f(((const unsigned short*)p)[i]);
    return ((const float*)p)[i];
}

__global__ void k_detect(const unsigned short* hw, int* flag){
    if (blockIdx.x == 0 && threadIdx.x == 0){
        int ok = 1;
        for (int j = 0; j < 64; ++j){
            float v = bf2f(hw[j]);
            if (!(v > 0.05f && v < 1.2f)) ok = 0;
        }
        *flag = ok;
    }
}

__global__ void k_sent(unsigned short* p, int n){
    int i = blockIdx.x*256 + threadIdx.x;
    if (i < n) p[i] = 0x4204;
}

__global__ void k_zero(float* p, int n){
    int i = blockIdx.x*256 + threadIdx.x;
    if (i < n) p[i] = 0.f;
}

// counts: weighted node degree D, node degree Dc, edge cardinality Bc
__global__ void k_count(const int* nidx, const int* eidx, const void* hw,
                        float* D, int* Dc, int* Bc, const int* flag){
    int bf = *flag;
    int i = blockIdx.x*256 + threadIdx.x;
    if (i < N_INC){
        atomicAdd(&D[nidx[i]], ldv(hw, eidx[i], bf));
        atomicAdd(&Dc[nidx[i]], 1);
        atomicAdd(&Bc[eidx[i]], 1);
    }
}

__global__ void k_invert(float* D, const int* Bc, float* Binv){
    int i = blockIdx.x*256 + threadIdx.x;
    if (i < N_NODES) D[i] = D[i] > 0.f ? 1.f/D[i] : 0.f;      // becomes Dinv
    if (i < N_EDGES) Binv[i] = Bc[i] > 0 ? 1.f/(float)Bc[i] : 0.f;
}

// ---- chunked exclusive scan, no LDS ----
__global__ void k_chunksum(const int* cnt, int* csum, int n, int nchunks){
    int ch = blockIdx.x*256 + threadIdx.x;
    if (ch >= nchunks) return;
    int beg = ch*128, end = beg + 128;
    if (end > n) end = n;
    int s = 0;
    for (int i = beg; i < end; ++i) s += cnt[i];
    csum[ch] = s;
}
__global__ void k_chunkscan(const int* csum, int* cbase, int nchunks){
    if (blockIdx.x == 0 && threadIdx.x == 0){
        int run = 0;
        for (int ch = 0; ch < nchunks; ++ch){
            cbase[ch] = run;
            run += csum[ch];
        }
    }
}
__global__ void k_chunkfill(const int* cnt, const int* cbase, int* indptr,
                            int* cursor, int n, int nchunks){
    int ch = blockIdx.x*256 + threadIdx.x;
    if (ch >= nchunks) return;
    int beg = ch*128, end = beg + 128;
    if (end > n) end = n;
    int run = cbase[ch];
    for (int i = beg; i < end; ++i){
        indptr[i] = run;
        cursor[i] = run;
        run += cnt[i];
    }
}

__global__ void k_fill(const int* nidx, const int* eidx,
                       int* cursor_n, int* nlist,
                       int* cursor_e, int* elist){
    int i = blockIdx.x*256 + threadIdx.x;
    if (i < N_INC){
        int pn = atomicAdd(&cursor_n[nidx[i]], 1);
        nlist[pn] = eidx[i];
        int pe = atomicAdd(&cursor_e[eidx[i]], 1);
        elist[pe] = nidx[i];
    }
}

// gate GEMM v2: register-tiled. Block = 16 nodes x 128 cols, 256 threads,
// 8 outputs/thread (one node, 8 consecutive cols). W rows stay L1-resident;
// 8 consecutive W reads merge into wide loads.
__global__ void k_gemm_gate(const void* x, const void* st, const void* W,
                            float* X1, const int* flag){
    int bf = *flag;
    int tid = threadIdx.x;
    int node = blockIdx.x*16 + (tid >> 4);
    int c0 = (tid & 15) * 8;
    if (node >= N_NODES) return;
    float a0=0.f,a1=0.f,a2=0.f,a3=0.f,a4=0.f,a5=0.f,a6=0.f,a7=0.f;
    if (bf){
        for (int k = 0; k < 64; ++k){
            float a = ldv(x, node*64 + k, 1);
            float b = ldv(st, node*64 + k, 1);
            const unsigned short* w0 = (const unsigned short*)W + k*128 + c0;
            const unsigned short* w1 = (const unsigned short*)W + (64+k)*128 + c0;
            a0 += a*bf2f(w0[0]) + b*bf2f(w1[0]);
            a1 += a*bf2f(w0[1]) + b*bf2f(w1[1]);
            a2 += a*bf2f(w0[2]) + b*bf2f(w1[2]);
            a3 += a*bf2f(w0[3]) + b*bf2f(w1[3]);
            a4 += a*bf2f(w0[4]) + b*bf2f(w1[4]);
            a5 += a*bf2f(w0[5]) + b*bf2f(w1[5]);
            a6 += a*bf2f(w0[6]) + b*bf2f(w1[6]);
            a7 += a*bf2f(w0[7]) + b*bf2f(w1[7]);
        }
    } else {
        const float* xf = (const float*)x;
        const float* sf = (const float*)st;
        const float* Wf = (const float*)W;
        for (int k = 0; k < 64; ++k){
            float a = xf[node*64 + k];
            float b = sf[node*64 + k];
            const float* w0 = Wf + k*128 + c0;
            const float* w1 = Wf + (64+k)*128 + c0;
            a0 += a*w0[0] + b*w1[0];
            a1 += a*w0[1] + b*w1[1];
            a2 += a*w0[2] + b*w1[2];
            a3 += a*w0[3] + b*w1[3];
            a4 += a*w0[4] + b*w1[4];
            a5 += a*w0[5] + b*w1[5];
            a6 += a*w0[6] + b*w1[6];
            a7 += a*w0[7] + b*w1[7];
        }
    }
    float* o = X1 + node*128 + c0;
    o[0]=a0; o[1]=a1; o[2]=a2; o[3]=a3; o[4]=a4; o[5]=a5; o[6]=a6; o[7]=a7;
}

// cand GEMM v2: same tiling. cols 0-63 from Wc (conv), 64-127 from Wr (residual).
// Each thread's 8-col strip lies entirely in one W (c0 multiple of 8).
__global__ void k_gemm_cand(const void* x, const float* rs, const void* Wc,
                            const void* Wr, float* X1, const int* flag){
    int bf = *flag;
    int tid = threadIdx.x;
    int node = blockIdx.x*16 + (tid >> 4);
    int cq = tid & 15;
    int c0 = cq * 8;
    int cc = c0 & 63;
    if (node >= N_NODES) return;
    const void* Wsel = (cq < 8) ? Wc : Wr;
    float a0=0.f,a1=0.f,a2=0.f,a3=0.f,a4=0.f,a5=0.f,a6=0.f,a7=0.f;
    if (bf){
        for (int k = 0; k < 64; ++k){
            float a = ldv(x, node*64 + k, 1);
            float r = rs[node*64 + k];
            const unsigned short* w0 = (const unsigned short*)Wsel + k*64 + cc;
            const unsigned short* w1 = (const unsigned short*)Wsel + (64+k)*64 + cc;
            a0 += a*bf2f(w0[0]) + r*bf2f(w1[0]);
            a1 += a*bf2f(w0[1]) + r*bf2f(w1[1]);
            a2 += a*bf2f(w0[2]) + r*bf2f(w1[2]);
            a3 += a*bf2f(w0[3]) + r*bf2f(w1[3]);
            a4 += a*bf2f(w0[4]) + r*bf2f(w1[4]);
            a5 += a*bf2f(w0[5]) + r*bf2f(w1[5]);
            a6 += a*bf2f(w0[6]) + r*bf2f(w1[6]);
            a7 += a*bf2f(w0[7]) + r*bf2f(w1[7]);
        }
    } else {
        const float* xf = (const float*)x;
        const float* Wf = (const float*)Wsel;
        for (int k = 0; k < 64; ++k){
            float a = xf[node*64 + k];
            float r = rs[node*64 + k];
            const float* w0 = Wf + k*64 + cc;
            const float* w1 = Wf + (64+k)*64 + cc;
            a0 += a*w0[0] + r*w1[0];
            a1 += a*w0[1] + r*w1[1];
            a2 += a*w0[2] + r*w1[2];
            a3 += a*w0[3] + r*w1[3];
            a4 += a*w0[4] + r*w1[4];
            a5 += a*w0[5] + r*w1[5];
            a6 += a*w0[6] + r*w1[6];
            a7 += a*w0[7] + r*w1[7];
        }
    }
    float* o = X1 + node*128 + c0;
    o[0]=a0; o[1]=a1; o[2]=a2; o[3]=a3; o[4]=a4; o[5]=a5; o[6]=a6; o[7]=a7;
}

// edge gather: m[e,c] = hw[e]*Binv[e] * sum_{n in e} X1[n,c]   (X1 ld = 128)
__global__ void k_gather_e(const int* indptr_e, const int* Bc, const int* elist,
                           const float* X1, const void* hw, const float* Binv,
                           float* m, int C, const int* flag){
    int bf = *flag;
    int t = blockIdx.x*256 + threadIdx.x;
    if (t >= N_EDGES*C) return;
    int e = t / C, c = t - e*C;
    int beg = indptr_e[e], cnt = Bc[e];
    float acc = 0.f;
    for (int j = 0; j < cnt; ++j){
        int n = elist[beg + j];
        acc += X1[n*128 + c];
    }
    m[e*C + c] = acc * ldv(hw, e, bf) * Binv[e];
}

// node gather: h[n,c] = sum_{e in N(n)} m[e,c]
__global__ void k_gather_n(const int* indptr_n, const int* Dc, const int* nlist,
                           const float* m, float* h, int C){
    int t = blockIdx.x*256 + threadIdx.x;
    if (t >= N_NODES*C) return;
    int n = t / C, c = t - n*C;
    int beg = indptr_n[n], cnt = Dc[n];
    float acc = 0.f;
    for (int j = 0; j < cnt; ++j){
        int e = nlist[beg + j];
        acc += m[e*C + c];
    }
    h[n*C + c] = acc;
}

// gate prep: thread per (node, 64-col half). Coalesced 256B/lane reads.
__global__ void k_prep_gate(const void* x, const void* st, const float* Dinv,
                            float* h, const void* gb, float* pstat,
                            const int* flag){
    int bf = *flag;
    int t = blockIdx.x*256 + threadIdx.x;
    if (t >= N_NODES*2) return;
    int n = t >> 1, half = t & 1;
    float di = Dinv[n];
    float s = 0.f, sq = 0.f;
    for (int j = 0; j < 64; ++j){
        int c = half*64 + j;
        float base = (half == 0) ? ldv(x, n*64 + j, bf) : ldv(st, n*64 + j, bf);
        float v = base + di*h[n*128 + c] + ldv(gb, c, bf);
        if (v < 0.f) v = 0.f;
        h[n*128 + c] = v;
        s += v; sq += v*v;
    }
    pstat[t*2]     = s;
    pstat[t*2 + 1] = sq;
}

// gate fin: thread per (node, col<64).
__global__ void k_gate_fin2(const void* st, const float* P, const float* pstat,
                            const void* lng, const void* lnb,
                            float* zbuf, float* rs, const int* flag){
    int bf = *flag;
    int t = blockIdx.x*256 + threadIdx.x;
    if (t >= N_NODES*64) return;
    int n = t >> 6, c = t & 63;
    float s  = pstat[4*n]     + pstat[4*n + 2];
    float sq = pstat[4*n + 1] + pstat[4*n + 3];
    float mu = s * (1.f/128.f);
    float var = sq * (1.f/128.f) - mu*mu;
    if (var < 0.f) var = 0.f;
    float inv = 1.f / sqrtf(var + 1e-5f);
    float v0 = P[n*128 + c];
    float v1 = P[n*128 + 64 + c];
    float u0 = (v0 - mu)*inv*ldv(lng, c, bf)      + ldv(lnb, c, bf);
    float u1 = (v1 - mu)*inv*ldv(lng, 64 + c, bf) + ldv(lnb, 64 + c, bf);
    float z = 1.f/(1.f + expf(-u0));
    float r = 1.f/(1.f + expf(-u1));
    float s1 = ldv(st, t, bf);
    zbuf[t] = z;
    rs[t]   = r * s1;
}

// cand prep: thread per node.
__global__ void k_prep_cand(const float* X1, const float* Dinv, float* h2,
                            const void* cbv, const void* crb, float* pstat,
                            const int* flag){
    int bf = *flag;
    int n = blockIdx.x*256 + threadIdx.x;
    if (n >= N_NODES) return;
    float di = Dinv[n];
    float s = 0.f, sq = 0.f;
    for (int c = 0; c < 64; ++c){
        float v = X1[n*128 + 64 + c] + ldv(crb, c, bf)
                + di*h2[n*64 + c] + ldv(cbv, c, bf);
        if (v < 0.f) v = 0.f;
        h2[n*64 + c] = v;
        s += v; sq += v*v;
    }
    pstat[n*2]     = s;
    pstat[n*2 + 1] = sq;
}

// cand fin: thread per (node, col). LN + tanh + GRU blend -> out.
__global__ void k_cand_fin2(const void* st, const float* P2, const float* pstat,
                            const void* lng, const void* lnb, const float* zbuf,
                            void* out, const int* flag){
    int bf = *flag;
    int t = blockIdx.x*256 + threadIdx.x;
    if (t >= N_NODES*64) return;
    int n = t >> 6, c = t & 63;
    float s  = pstat[2*n];
    float sq = pstat[2*n + 1];
    float mu = s * (1.f/64.f);
    float var = sq * (1.f/64.f) - mu*mu;
    if (var < 0.f) var = 0.f;
    float inv = 1.f / sqrtf(var + 1e-5f);
    float v = P2[t];
    float u = (v - mu)*inv*ldv(lng, c, bf) + ldv(lnb, c, bf);
    float hc = tanhf(u);
    float z = zbuf[t];
    float sv = ldv(st, t, bf);
    float res = (1.f - z)*sv + z*hc;
    if (bf) ((unsigned short*)out)[t] = f2bf(res);
    else    ((float*)out)[t] = res;
}

extern "C" void kernel_launch(void* const* d_in, const int* in_sizes, int n_in,
                              void* d_out, int out_size, void* d_ws, size_t ws_size,
                              hipStream_t stream){
    const void* x      = d_in[0];
    const void* state  = d_in[1];
    const int*  hidx   = (const int*)d_in[2];
    const void* hw     = d_in[3];
    const void* gate_W = d_in[4];
    const void* gate_b = d_in[5];
    const void* glng   = d_in[6];
    const void* glnb   = d_in[7];
    const void* cand_W = d_in[8];
    const void* cand_b = d_in[9];
    const void* clng   = d_in[10];
    const void* clnb   = d_in[11];
    const void* crW    = d_in[12];
    const void* crb    = d_in[13];
    (void)in_sizes; (void)n_in; (void)ws_size;

    const int* nidx = hidx;
    const int* eidx = hidx + N_INC;

    const int NCH_N = (N_NODES + 127)/128;   // 391
    const int NCH_E = (N_EDGES + 127)/128;   // 79

    // ---- workspace (byte offsets, 256B-aligned, total ~77.7 MB) ----
    char* w = (char*)d_ws;
    int*   flag     = (int*)  (w);
    float* D        = (float*)(w + 256);        // 50048 f  (-> Dinv)
    int*   Bc       = (int*)  (w + 200448);     // 10048 i
    int*   Dc       = (int*)  (w + 240640);     // 50048 i   (D,Bc,Dc contiguous: zeroed)
    float* Binv     = (float*)(w + 440832);     // 10048 f
    int*   indptr_n = (int*)  (w + 481024);     // 50048 i
    int*   cursor_n = (int*)  (w + 681216);     // 50048 i
    int*   indptr_e = (int*)  (w + 881408);     // 10048 i
    int*   cursor_e = (int*)  (w + 921600);     // 10048 i
    int*   csum_n   = (int*)  (w + 961792);     // 512 i
    int*   cbase_n  = (int*)  (w + 963840);     // 512 i
    int*   csum_e   = (int*)  (w + 965888);     // 256 i
    int*   cbase_e  = (int*)  (w + 966912);     // 256 i
    int*   nlist    = (int*)  (w + 967936);     // 800000 i
    int*   elist    = (int*)  (w + 4167936);    // 800000 i
    float* m        = (float*)(w + 7367936);    // 10000*128 f
    float* X1h      = (float*)(w + 12487936);   // 50000*128 f  (X1 / gate h / gate P)
    float* h2       = (float*)(w + 38087936);   // 50000*64 f   (cand h / cand P)
    float* zbuf     = (float*)(w + 50887936);   // 50000*64 f
    float* rs       = (float*)(w + 63687936);   // 50000*64 f
    float* pstat_g  = (float*)(w + 76487936);   // 200000 f
    float* pstat_c  = (float*)(w + 77288704);   // 100000 f -> ends 77688704

    // dtype detect + sentinel
    k_detect<<<1, 64, 0, stream>>>((const unsigned short*)hw, flag);
    k_sent<<<(out_size + 255)/256, 256, 0, stream>>>((unsigned short*)d_out, out_size);

    // zero D,Bc,Dc (contiguous 110144 words)
    k_zero<<<(110144 + 255)/256, 256, 0, stream>>>(D, 110144);

    // degrees + CSR build
    k_count<<<(N_INC + 255)/256, 256, 0, stream>>>(nidx, eidx, hw, D, Dc, Bc, flag);
    k_invert<<<(N_NODES + 255)/256, 256, 0, stream>>>(D, Bc, Binv);
    k_chunksum<<<(NCH_N + 255)/256, 256, 0, stream>>>(Dc, csum_n, N_NODES, NCH_N);
    k_chunkscan<<<1, 64, 0, stream>>>(csum_n, cbase_n, NCH_N);
    k_chunkfill<<<(NCH_N + 255)/256, 256, 0, stream>>>(Dc, cbase_n, indptr_n, cursor_n,
                                                       N_NODES, NCH_N);
    k_chunksum<<<(NCH_E + 255)/256, 256, 0, stream>>>(Bc, csum_e, N_EDGES, NCH_E);
    k_chunkscan<<<1, 64, 0, stream>>>(csum_e, cbase_e, NCH_E);
    k_chunkfill<<<(NCH_E + 255)/256, 256, 0, stream>>>(Bc, cbase_e, indptr_e, cursor_e,
                                                       N_EDGES, NCH_E);
    k_fill<<<(N_INC + 255)/256, 256, 0, stream>>>(nidx, eidx, cursor_n, nlist,
                                                  cursor_e, elist);

    // ---- gate path ----
    k_gemm_gate<<<N_NODES/16, 256, 0, stream>>>(x, state, gate_W, X1h, flag);
    k_gather_e<<<(N_EDGES*128 + 255)/256, 256, 0, stream>>>(indptr_e, Bc, elist, X1h,
                                                            hw, Binv, m, 128, flag);
    k_gather_n<<<(N_NODES*128 + 255)/256, 256, 0, stream>>>(indptr_n, Dc, nlist, m,
                                                            X1h, 128);   // X1 dead -> h
    k_prep_gate<<<(N_NODES*2 + 255)/256, 256, 0, stream>>>(x, state, D, X1h, gate_b,
                                                           pstat_g, flag);
    k_gate_fin2<<<(N_NODES*64 + 255)/256, 256, 0, stream>>>(state, X1h, pstat_g,
                                                            glng, glnb, zbuf, rs, flag);

    // ---- candidate path ----
    k_gemm_cand<<<N_NODES/16, 256, 0, stream>>>(x, rs, cand_W, crW, X1h, flag);
    k_gather_e<<<(N_EDGES*64 + 255)/256, 256, 0, stream>>>(indptr_e, Bc, elist, X1h,
                                                           hw, Binv, m, 64, flag);
    k_gather_n<<<(N_NODES*64 + 255)/256, 256, 0, stream>>>(indptr_n, Dc, nlist, m,
                                                           h2, 64);
    k_prep_cand<<<(N_NODES + 255)/256, 256, 0, stream>>>(X1h, D, h2, cand_b, crb,
                                                         pstat_c, flag);
    k_cand_fin2<<<(N_NODES*64 + 255)/256, 256, 0, stream>>>(state, h2, pstat_c,
                                                            clng, clnb, zbuf,
                                                            d_out, flag);
}

// Round 12
// 1276.008 us; speedup vs baseline: 1.7698x; 1.0618x over previous
//
#include <hip/hip_runtime.h>

#define N_NODES 50000
#define N_EDGES 10000
#define N_INC   800000
// IN_F=64, HID=64, concat width 128.
// Input dtype (f32 vs raw-bf16) detected on device (k_detect) — f32 confirmed in R8.
// X1 intermediate stored as bf16 (u16) to halve the random-gather working set.

__device__ float bf2f(unsigned short u){
    return __uint_as_float(((unsigned)u) << 16);
}
__device__ unsigned short f2bf(float f){
    unsigned u = __float_as_uint(f);
    unsigned r = u + 0x7FFFu + ((u >> 16) & 1u);
    return (unsigned short)(r >> 16);
}
__device__ float ldv(const void* p, int i, int bf){
    if (bf) return bf2f(((const unsigned short*)p)[i]);
    return ((const float*)p)[i];
}

__global__ void k_detect(const unsigned short* hw, int* flag){
    if (blockIdx.x == 0 && threadIdx.x == 0){
        int ok = 1;
        for (int j = 0; j < 64; ++j){
            float v = bf2f(hw[j]);
            if (!(v > 0.05f && v < 1.2f)) ok = 0;
        }
        *flag = ok;
    }
}

__global__ void k_sent(unsigned short* p, int n){
    int i = blockIdx.x*256 + threadIdx.x;
    if (i < n) p[i] = 0x4204;
}

__global__ void k_zero(float* p, int n){
    int i = blockIdx.x*256 + threadIdx.x;
    if (i < n) p[i] = 0.f;
}

// counts: weighted node degree D, node degree Dc, edge cardinality Bc
__global__ void k_count(const int* nidx, const int* eidx, const void* hw,
                        float* D, int* Dc, int* Bc, const int* flag){
    int bf = *flag;
    int i = blockIdx.x*256 + threadIdx.x;
    if (i < N_INC){
        atomicAdd(&D[nidx[i]], ldv(hw, eidx[i], bf));
        atomicAdd(&Dc[nidx[i]], 1);
        atomicAdd(&Bc[eidx[i]], 1);
    }
}

__global__ void k_invert(float* D, const int* Bc, float* Binv){
    int i = blockIdx.x*256 + threadIdx.x;
    if (i < N_NODES) D[i] = D[i] > 0.f ? 1.f/D[i] : 0.f;      // becomes Dinv
    if (i < N_EDGES) Binv[i] = Bc[i] > 0 ? 1.f/(float)Bc[i] : 0.f;
}

// ---- chunked exclusive scan, no LDS ----
__global__ void k_chunksum(const int* cnt, int* csum, int n, int nchunks){
    int ch = blockIdx.x*256 + threadIdx.x;
    if (ch >= nchunks) return;
    int beg = ch*128, end = beg + 128;
    if (end > n) end = n;
    int s = 0;
    for (int i = beg; i < end; ++i) s += cnt[i];
    csum[ch] = s;
}
__global__ void k_chunkscan(const int* csum, int* cbase, int nchunks){
    if (blockIdx.x == 0 && threadIdx.x == 0){
        int run = 0;
        for (int ch = 0; ch < nchunks; ++ch){
            cbase[ch] = run;
            run += csum[ch];
        }
    }
}
__global__ void k_chunkfill(const int* cnt, const int* cbase, int* indptr,
                            int* cursor, int n, int nchunks){
    int ch = blockIdx.x*256 + threadIdx.x;
    if (ch >= nchunks) return;
    int beg = ch*128, end = beg + 128;
    if (end > n) end = n;
    int run = cbase[ch];
    for (int i = beg; i < end; ++i){
        indptr[i] = run;
        cursor[i] = run;
        run += cnt[i];
    }
}

__global__ void k_fill(const int* nidx, const int* eidx,
                       int* cursor_n, int* nlist,
                       int* cursor_e, int* elist){
    int i = blockIdx.x*256 + threadIdx.x;
    if (i < N_INC){
        int pn = atomicAdd(&cursor_n[nidx[i]], 1);
        nlist[pn] = eidx[i];
        int pe = atomicAdd(&cursor_e[eidx[i]], 1);
        elist[pe] = nidx[i];
    }
}

// gate GEMM: register-tiled, 8 outputs/thread, bf16 X1 out.
__global__ void k_gemm_gate(const void* x, const void* st, const void* W,
                            unsigned short* X1b, const int* flag){
    int bf = *flag;
    int tid = threadIdx.x;
    int node = blockIdx.x*16 + (tid >> 4);
    int c0 = (tid & 15) * 8;
    if (node >= N_NODES) return;
    float a0=0.f,a1=0.f,a2=0.f,a3=0.f,a4=0.f,a5=0.f,a6=0.f,a7=0.f;
    if (bf){
        for (int k = 0; k < 64; ++k){
            float a = ldv(x, node*64 + k, 1);
            float b = ldv(st, node*64 + k, 1);
            const unsigned short* w0 = (const unsigned short*)W + k*128 + c0;
            const unsigned short* w1 = (const unsigned short*)W + (64+k)*128 + c0;
            a0 += a*bf2f(w0[0]) + b*bf2f(w1[0]);
            a1 += a*bf2f(w0[1]) + b*bf2f(w1[1]);
            a2 += a*bf2f(w0[2]) + b*bf2f(w1[2]);
            a3 += a*bf2f(w0[3]) + b*bf2f(w1[3]);
            a4 += a*bf2f(w0[4]) + b*bf2f(w1[4]);
            a5 += a*bf2f(w0[5]) + b*bf2f(w1[5]);
            a6 += a*bf2f(w0[6]) + b*bf2f(w1[6]);
            a7 += a*bf2f(w0[7]) + b*bf2f(w1[7]);
        }
    } else {
        const float* xf = (const float*)x;
        const float* sf = (const float*)st;
        const float* Wf = (const float*)W;
        for (int k = 0; k < 64; ++k){
            float a = xf[node*64 + k];
            float b = sf[node*64 + k];
            const float* w0 = Wf + k*128 + c0;
            const float* w1 = Wf + (64+k)*128 + c0;
            a0 += a*w0[0] + b*w1[0];
            a1 += a*w0[1] + b*w1[1];
            a2 += a*w0[2] + b*w1[2];
            a3 += a*w0[3] + b*w1[3];
            a4 += a*w0[4] + b*w1[4];
            a5 += a*w0[5] + b*w1[5];
            a6 += a*w0[6] + b*w1[6];
            a7 += a*w0[7] + b*w1[7];
        }
    }
    unsigned short* o = X1b + node*128 + c0;
    o[0]=f2bf(a0); o[1]=f2bf(a1); o[2]=f2bf(a2); o[3]=f2bf(a3);
    o[4]=f2bf(a4); o[5]=f2bf(a5); o[6]=f2bf(a6); o[7]=f2bf(a7);
}

// cand GEMM: cols 0-63 from Wc, 64-127 from Wr; bf16 X1 out.
__global__ void k_gemm_cand(const void* x, const float* rs, const void* Wc,
                            const void* Wr, unsigned short* X1b, const int* flag){
    int bf = *flag;
    int tid = threadIdx.x;
    int node = blockIdx.x*16 + (tid >> 4);
    int cq = tid & 15;
    int c0 = cq * 8;
    int cc = c0 & 63;
    if (node >= N_NODES) return;
    const void* Wsel = (cq < 8) ? Wc : Wr;
    float a0=0.f,a1=0.f,a2=0.f,a3=0.f,a4=0.f,a5=0.f,a6=0.f,a7=0.f;
    if (bf){
        for (int k = 0; k < 64; ++k){
            float a = ldv(x, node*64 + k, 1);
            float r = rs[node*64 + k];
            const unsigned short* w0 = (const unsigned short*)Wsel + k*64 + cc;
            const unsigned short* w1 = (const unsigned short*)Wsel + (64+k)*64 + cc;
            a0 += a*bf2f(w0[0]) + r*bf2f(w1[0]);
            a1 += a*bf2f(w0[1]) + r*bf2f(w1[1]);
            a2 += a*bf2f(w0[2]) + r*bf2f(w1[2]);
            a3 += a*bf2f(w0[3]) + r*bf2f(w1[3]);
            a4 += a*bf2f(w0[4]) + r*bf2f(w1[4]);
            a5 += a*bf2f(w0[5]) + r*bf2f(w1[5]);
            a6 += a*bf2f(w0[6]) + r*bf2f(w1[6]);
            a7 += a*bf2f(w0[7]) + r*bf2f(w1[7]);
        }
    } else {
        const float* xf = (const float*)x;
        const float* Wf = (const float*)Wsel;
        for (int k = 0; k < 64; ++k){
            float a = xf[node*64 + k];
            float r = rs[node*64 + k];
            const float* w0 = Wf + k*64 + cc;
            const float* w1 = Wf + (64+k)*64 + cc;
            a0 += a*w0[0] + r*w1[0];
            a1 += a*w0[1] + r*w1[1];
            a2 += a*w0[2] + r*w1[2];
            a3 += a*w0[3] + r*w1[3];
            a4 += a*w0[4] + r*w1[4];
            a5 += a*w0[5] + r*w1[5];
            a6 += a*w0[6] + r*w1[6];
            a7 += a*w0[7] + r*w1[7];
        }
    }
    unsigned short* o = X1b + node*128 + c0;
    o[0]=f2bf(a0); o[1]=f2bf(a1); o[2]=f2bf(a2); o[3]=f2bf(a3);
    o[4]=f2bf(a4); o[5]=f2bf(a5); o[6]=f2bf(a6); o[7]=f2bf(a7);
}

// edge gather v2: bf16 X1, 2 cols/thread via one u32 load, 32 threads/edge.
// pairBase selects the 64-col half (0 or 32) -> small working set per pass.
__global__ void k_gather_e2(const int* indptr_e, const int* Bc, const int* elist,
                            const unsigned short* X1b, const void* hw,
                            const float* Binv, float* m, int pairBase, int C,
                            const int* flag){
    int bf = *flag;
    int t = blockIdx.x*256 + threadIdx.x;
    if (t >= N_EDGES*32) return;
    int e = t >> 5, p = t & 31;
    int cp = pairBase + p;
    int beg = indptr_e[e], cnt = Bc[e];
    float acc0 = 0.f, acc1 = 0.f;
    for (int j = 0; j < cnt; ++j){
        int n = elist[beg + j];
        unsigned v = *(const unsigned*)(X1b + n*128 + cp*2);
        acc0 += bf2f((unsigned short)(v & 0xFFFFu));
        acc1 += bf2f((unsigned short)(v >> 16));
    }
    float wsc = ldv(hw, e, bf) * Binv[e];
    m[e*C + cp*2]     = acc0 * wsc;
    m[e*C + cp*2 + 1] = acc1 * wsc;
}

// node gather: h[n,c] = sum_{e in N(n)} m[e,c]
__global__ void k_gather_n(const int* indptr_n, const int* Dc, const int* nlist,
                           const float* m, float* h, int C){
    int t = blockIdx.x*256 + threadIdx.x;
    if (t >= N_NODES*C) return;
    int n = t / C, c = t - n*C;
    int beg = indptr_n[n], cnt = Dc[n];
    float acc = 0.f;
    for (int j = 0; j < cnt; ++j){
        int e = nlist[beg + j];
        acc += m[e*C + c];
    }
    h[n*C + c] = acc;
}

// gate prep: thread per (node, 64-col half); v = relu(base + Dinv*h + gb) in place.
__global__ void k_prep_gate(const void* x, const void* st, const float* Dinv,
                            float* h, const void* gb, float* pstat,
                            const int* flag){
    int bf = *flag;
    int t = blockIdx.x*256 + threadIdx.x;
    if (t >= N_NODES*2) return;
    int n = t >> 1, half = t & 1;
    float di = Dinv[n];
    float s = 0.f, sq = 0.f;
    for (int j = 0; j < 64; ++j){
        int c = half*64 + j;
        float base = (half == 0) ? ldv(x, n*64 + j, bf) : ldv(st, n*64 + j, bf);
        float v = base + di*h[n*128 + c] + ldv(gb, c, bf);
        if (v < 0.f) v = 0.f;
        h[n*128 + c] = v;
        s += v; sq += v*v;
    }
    pstat[t*2]     = s;
    pstat[t*2 + 1] = sq;
}

// gate fin: thread per (node, col<64).
__global__ void k_gate_fin2(const void* st, const float* P, const float* pstat,
                            const void* lng, const void* lnb,
                            float* zbuf, float* rs, const int* flag){
    int bf = *flag;
    int t = blockIdx.x*256 + threadIdx.x;
    if (t >= N_NODES*64) return;
    int n = t >> 6, c = t & 63;
    float s  = pstat[4*n]     + pstat[4*n + 2];
    float sq = pstat[4*n + 1] + pstat[4*n + 3];
    float mu = s * (1.f/128.f);
    float var = sq * (1.f/128.f) - mu*mu;
    if (var < 0.f) var = 0.f;
    float inv = 1.f / sqrtf(var + 1e-5f);
    float v0 = P[n*128 + c];
    float v1 = P[n*128 + 64 + c];
    float u0 = (v0 - mu)*inv*ldv(lng, c, bf)      + ldv(lnb, c, bf);
    float u1 = (v1 - mu)*inv*ldv(lng, 64 + c, bf) + ldv(lnb, 64 + c, bf);
    float z = 1.f/(1.f + expf(-u0));
    float r = 1.f/(1.f + expf(-u1));
    float s1 = ldv(st, t, bf);
    zbuf[t] = z;
    rs[t]   = r * s1;
}

// cand prep: thread per node; residual from bf16 X1.
__global__ void k_prep_cand(const unsigned short* X1b, const float* Dinv, float* h2,
                            const void* cbv, const void* crb, float* pstat,
                            const int* flag){
    int bf = *flag;
    int n = blockIdx.x*256 + threadIdx.x;
    if (n >= N_NODES) return;
    float di = Dinv[n];
    float s = 0.f, sq = 0.f;
    for (int c = 0; c < 64; ++c){
        float v = bf2f(X1b[n*128 + 64 + c]) + ldv(crb, c, bf)
                + di*h2[n*64 + c] + ldv(cbv, c, bf);
        if (v < 0.f) v = 0.f;
        h2[n*64 + c] = v;
        s += v; sq += v*v;
    }
    pstat[n*2]     = s;
    pstat[n*2 + 1] = sq;
}

// cand fin: thread per (node, col). LN + tanh + GRU blend -> out.
__global__ void k_cand_fin2(const void* st, const float* P2, const float* pstat,
                            const void* lng, const void* lnb, const float* zbuf,
                            void* out, const int* flag){
    int bf = *flag;
    int t = blockIdx.x*256 + threadIdx.x;
    if (t >= N_NODES*64) return;
    int n = t >> 6, c = t & 63;
    float s  = pstat[2*n];
    float sq = pstat[2*n + 1];
    float mu = s * (1.f/64.f);
    float var = sq * (1.f/64.f) - mu*mu;
    if (var < 0.f) var = 0.f;
    float inv = 1.f / sqrtf(var + 1e-5f);
    float v = P2[t];
    float u = (v - mu)*inv*ldv(lng, c, bf) + ldv(lnb, c, bf);
    float hc = tanhf(u);
    float z = zbuf[t];
    float sv = ldv(st, t, bf);
    float res = (1.f - z)*sv + z*hc;
    if (bf) ((unsigned short*)out)[t] = f2bf(res);
    else    ((float*)out)[t] = res;
}

extern "C" void kernel_launch(void* const* d_in, const int* in_sizes, int n_in,
                              void* d_out, int out_size, void* d_ws, size_t ws_size,
                              hipStream_t stream){
    const void* x      = d_in[0];
    const void* state  = d_in[1];
    const int*  hidx   = (const int*)d_in[2];
    const void* hw     = d_in[3];
    const void* gate_W = d_in[4];
    const void* gate_b = d_in[5];
    const void* glng   = d_in[6];
    const void* glnb   = d_in[7];
    const void* cand_W = d_in[8];
    const void* cand_b = d_in[9];
    const void* clng   = d_in[10];
    const void* clnb   = d_in[11];
    const void* crW    = d_in[12];
    const void* crb    = d_in[13];
    (void)in_sizes; (void)n_in; (void)ws_size;

    const int* nidx = hidx;
    const int* eidx = hidx + N_INC;

    const int NCH_N = (N_NODES + 127)/128;   // 391
    const int NCH_E = (N_EDGES + 127)/128;   // 79

    // ---- workspace (byte offsets, 256B-aligned, total ~77.7 MB) ----
    char* w = (char*)d_ws;
    int*   flag     = (int*)  (w);
    float* D        = (float*)(w + 256);        // 50048 f  (-> Dinv)
    int*   Bc       = (int*)  (w + 200448);     // 10048 i
    int*   Dc       = (int*)  (w + 240640);     // 50048 i   (D,Bc,Dc contiguous: zeroed)
    float* Binv     = (float*)(w + 440832);     // 10048 f
    int*   indptr_n = (int*)  (w + 481024);     // 50048 i
    int*   cursor_n = (int*)  (w + 681216);     // 50048 i
    int*   indptr_e = (int*)  (w + 881408);     // 10048 i
    int*   cursor_e = (int*)  (w + 921600);     // 10048 i
    int*   csum_n   = (int*)  (w + 961792);     // 512 i
    int*   cbase_n  = (int*)  (w + 963840);     // 512 i
    int*   csum_e   = (int*)  (w + 965888);     // 256 i
    int*   cbase_e  = (int*)  (w + 966912);     // 256 i
    int*   nlist    = (int*)  (w + 967936);     // 800000 i
    int*   elist    = (int*)  (w + 4167936);    // 800000 i
    float* m        = (float*)(w + 7367936);    // 10000*128 f
    unsigned short* X1b = (unsigned short*)(w + 12487936);  // 50000*128 u16
    float* hg       = (float*)(w + 25287936);   // 50000*128 f (gate h/P; cand h2 aliases)
    float* h2       = hg;                        // cand h/P2 (gate hg dead by then)
    float* zbuf     = (float*)(w + 50887936);   // 50000*64 f
    float* rs       = (float*)(w + 63687936);   // 50000*64 f
    float* pstat_g  = (float*)(w + 76487936);   // 200000 f
    float* pstat_c  = (float*)(w + 77287936);   // 100000 f -> ends 77687936

    // dtype detect + sentinel
    k_detect<<<1, 64, 0, stream>>>((const unsigned short*)hw, flag);
    k_sent<<<(out_size + 255)/256, 256, 0, stream>>>((unsigned short*)d_out, out_size);

    // zero D,Bc,Dc (contiguous 110144 words)
    k_zero<<<(110144 + 255)/256, 256, 0, stream>>>(D, 110144);

    // degrees + CSR build
    k_count<<<(N_INC + 255)/256, 256, 0, stream>>>(nidx, eidx, hw, D, Dc, Bc, flag);
    k_invert<<<(N_NODES + 255)/256, 256, 0, stream>>>(D, Bc, Binv);
    k_chunksum<<<(NCH_N + 255)/256, 256, 0, stream>>>(Dc, csum_n, N_NODES, NCH_N);
    k_chunkscan<<<1, 64, 0, stream>>>(csum_n, cbase_n, NCH_N);
    k_chunkfill<<<(NCH_N + 255)/256, 256, 0, stream>>>(Dc, cbase_n, indptr_n, cursor_n,
                                                       N_NODES, NCH_N);
    k_chunksum<<<(NCH_E + 255)/256, 256, 0, stream>>>(Bc, csum_e, N_EDGES, NCH_E);
    k_chunkscan<<<1, 64, 0, stream>>>(csum_e, cbase_e, NCH_E);
    k_chunkfill<<<(NCH_E + 255)/256, 256, 0, stream>>>(Bc, cbase_e, indptr_e, cursor_e,
                                                       N_EDGES, NCH_E);
    k_fill<<<(N_INC + 255)/256, 256, 0, stream>>>(nidx, eidx, cursor_n, nlist,
                                                  cursor_e, elist);

    // ---- gate path ----
    k_gemm_gate<<<N_NODES/16, 256, 0, stream>>>(x, state, gate_W, X1b, flag);
    k_gather_e2<<<(N_EDGES*32 + 255)/256, 256, 0, stream>>>(indptr_e, Bc, elist, X1b,
                                                            hw, Binv, m, 0, 128, flag);
    k_gather_e2<<<(N_EDGES*32 + 255)/256, 256, 0, stream>>>(indptr_e, Bc, elist, X1b,
                                                            hw, Binv, m, 32, 128, flag);
    k_gather_n<<<(N_NODES*128 + 255)/256, 256, 0, stream>>>(indptr_n, Dc, nlist, m,
                                                            hg, 128);
    k_prep_gate<<<(N_NODES*2 + 255)/256, 256, 0, stream>>>(x, state, D, hg, gate_b,
                                                           pstat_g, flag);
    k_gate_fin2<<<(N_NODES*64 + 255)/256, 256, 0, stream>>>(state, hg, pstat_g,
                                                            glng, glnb, zbuf, rs, flag);

    // ---- candidate path ----
    k_gemm_cand<<<N_NODES/16, 256, 0, stream>>>(x, rs, cand_W, crW, X1b, flag);
    k_gather_e2<<<(N_EDGES*32 + 255)/256, 256, 0, stream>>>(indptr_e, Bc, elist, X1b,
                                                            hw, Binv, m, 0, 64, flag);
    k_gather_n<<<(N_NODES*64 + 255)/256, 256, 0, stream>>>(indptr_n, Dc, nlist, m,
                                                           h2, 64);
    k_prep_cand<<<(N_NODES + 255)/256, 256, 0, stream>>>(X1b, D, h2, cand_b, crb,
                                                         pstat_c, flag);
    k_cand_fin2<<<(N_NODES*64 + 255)/256, 256, 0, stream>>>(state, h2, pstat_c,
                                                            clng, clnb, zbuf,
                                                            d_out, flag);
}

// Round 14
// 1131.173 us; speedup vs baseline: 1.9964x; 1.1280x over previous
//
#include <hip/hip_runtime.h>

#define N_NODES 50000
#define N_EDGES 10000
#define N_INC   800000
// IN_F=64, HID=64, concat width 128.
// Input dtype (f32 vs raw-bf16) detected on device (k_detect) — f32 confirmed in R8.
// X1 intermediate stored as bf16 (u16) to halve the random-gather working set.
// R14 = byte-identical resubmit of R13 (SIGABRT suspected infra flake; audit clean).

__device__ float bf2f(unsigned short u){
    return __uint_as_float(((unsigned)u) << 16);
}
__device__ unsigned short f2bf(float f){
    unsigned u = __float_as_uint(f);
    unsigned r = u + 0x7FFFu + ((u >> 16) & 1u);
    return (unsigned short)(r >> 16);
}
__device__ float ldv(const void* p, int i, int bf){
    if (bf) return bf2f(((const unsigned short*)p)[i]);
    return ((const float*)p)[i];
}

__global__ void k_detect(const unsigned short* hw, int* flag){
    if (blockIdx.x == 0 && threadIdx.x == 0){
        int ok = 1;
        for (int j = 0; j < 64; ++j){
            float v = bf2f(hw[j]);
            if (!(v > 0.05f && v < 1.2f)) ok = 0;
        }
        *flag = ok;
    }
}

__global__ void k_sent(unsigned short* p, int n){
    int i = blockIdx.x*256 + threadIdx.x;
    if (i < n) p[i] = 0x4204;
}

__global__ void k_zero(float* p, int n){
    int i = blockIdx.x*256 + threadIdx.x;
    if (i < n) p[i] = 0.f;
}

// counts: weighted node degree D, node degree Dc, edge cardinality Bc
__global__ void k_count(const int* nidx, const int* eidx, const void* hw,
                        float* D, int* Dc, int* Bc, const int* flag){
    int bf = *flag;
    int i = blockIdx.x*256 + threadIdx.x;
    if (i < N_INC){
        atomicAdd(&D[nidx[i]], ldv(hw, eidx[i], bf));
        atomicAdd(&Dc[nidx[i]], 1);
        atomicAdd(&Bc[eidx[i]], 1);
    }
}

__global__ void k_invert(float* D, const int* Bc, float* Binv){
    int i = blockIdx.x*256 + threadIdx.x;
    if (i < N_NODES) D[i] = D[i] > 0.f ? 1.f/D[i] : 0.f;      // becomes Dinv
    if (i < N_EDGES) Binv[i] = Bc[i] > 0 ? 1.f/(float)Bc[i] : 0.f;
}

// ---- chunked exclusive scan, no LDS ----
__global__ void k_chunksum(const int* cnt, int* csum, int n, int nchunks){
    int ch = blockIdx.x*256 + threadIdx.x;
    if (ch >= nchunks) return;
    int beg = ch*128, end = beg + 128;
    if (end > n) end = n;
    int s = 0;
    for (int i = beg; i < end; ++i) s += cnt[i];
    csum[ch] = s;
}
__global__ void k_chunkscan(const int* csum, int* cbase, int nchunks){
    if (blockIdx.x == 0 && threadIdx.x == 0){
        int run = 0;
        for (int ch = 0; ch < nchunks; ++ch){
            cbase[ch] = run;
            run += csum[ch];
        }
    }
}
__global__ void k_chunkfill(const int* cnt, const int* cbase, int* indptr,
                            int* cursor, int n, int nchunks){
    int ch = blockIdx.x*256 + threadIdx.x;
    if (ch >= nchunks) return;
    int beg = ch*128, end = beg + 128;
    if (end > n) end = n;
    int run = cbase[ch];
    for (int i = beg; i < end; ++i){
        indptr[i] = run;
        cursor[i] = run;
        run += cnt[i];
    }
}

__global__ void k_fill(const int* nidx, const int* eidx,
                       int* cursor_n, int* nlist,
                       int* cursor_e, int* elist){
    int i = blockIdx.x*256 + threadIdx.x;
    if (i < N_INC){
        int pn = atomicAdd(&cursor_n[nidx[i]], 1);
        nlist[pn] = eidx[i];
        int pe = atomicAdd(&cursor_e[eidx[i]], 1);
        elist[pe] = nidx[i];
    }
}

// gate GEMM: register-tiled, 8 outputs/thread, bf16 X1 out.
__global__ void k_gemm_gate(const void* x, const void* st, const void* W,
                            unsigned short* X1b, const int* flag){
    int bf = *flag;
    int tid = threadIdx.x;
    int node = blockIdx.x*16 + (tid >> 4);
    int c0 = (tid & 15) * 8;
    if (node >= N_NODES) return;
    float a0=0.f,a1=0.f,a2=0.f,a3=0.f,a4=0.f,a5=0.f,a6=0.f,a7=0.f;
    if (bf){
        for (int k = 0; k < 64; ++k){
            float a = ldv(x, node*64 + k, 1);
            float b = ldv(st, node*64 + k, 1);
            const unsigned short* w0 = (const unsigned short*)W + k*128 + c0;
            const unsigned short* w1 = (const unsigned short*)W + (64+k)*128 + c0;
            a0 += a*bf2f(w0[0]) + b*bf2f(w1[0]);
            a1 += a*bf2f(w0[1]) + b*bf2f(w1[1]);
            a2 += a*bf2f(w0[2]) + b*bf2f(w1[2]);
            a3 += a*bf2f(w0[3]) + b*bf2f(w1[3]);
            a4 += a*bf2f(w0[4]) + b*bf2f(w1[4]);
            a5 += a*bf2f(w0[5]) + b*bf2f(w1[5]);
            a6 += a*bf2f(w0[6]) + b*bf2f(w1[6]);
            a7 += a*bf2f(w0[7]) + b*bf2f(w1[7]);
        }
    } else {
        const float* xf = (const float*)x;
        const float* sf = (const float*)st;
        const float* Wf = (const float*)W;
        for (int k = 0; k < 64; ++k){
            float a = xf[node*64 + k];
            float b = sf[node*64 + k];
            const float* w0 = Wf + k*128 + c0;
            const float* w1 = Wf + (64+k)*128 + c0;
            a0 += a*w0[0] + b*w1[0];
            a1 += a*w0[1] + b*w1[1];
            a2 += a*w0[2] + b*w1[2];
            a3 += a*w0[3] + b*w1[3];
            a4 += a*w0[4] + b*w1[4];
            a5 += a*w0[5] + b*w1[5];
            a6 += a*w0[6] + b*w1[6];
            a7 += a*w0[7] + b*w1[7];
        }
    }
    unsigned short* o = X1b + node*128 + c0;
    o[0]=f2bf(a0); o[1]=f2bf(a1); o[2]=f2bf(a2); o[3]=f2bf(a3);
    o[4]=f2bf(a4); o[5]=f2bf(a5); o[6]=f2bf(a6); o[7]=f2bf(a7);
}

// cand GEMM: cols 0-63 from Wc, 64-127 from Wr; bf16 X1 out.
__global__ void k_gemm_cand(const void* x, const float* rs, const void* Wc,
                            const void* Wr, unsigned short* X1b, const int* flag){
    int bf = *flag;
    int tid = threadIdx.x;
    int node = blockIdx.x*16 + (tid >> 4);
    int cq = tid & 15;
    int c0 = cq * 8;
    int cc = c0 & 63;
    if (node >= N_NODES) return;
    const void* Wsel = (cq < 8) ? Wc : Wr;
    float a0=0.f,a1=0.f,a2=0.f,a3=0.f,a4=0.f,a5=0.f,a6=0.f,a7=0.f;
    if (bf){
        for (int k = 0; k < 64; ++k){
            float a = ldv(x, node*64 + k, 1);
            float r = rs[node*64 + k];
            const unsigned short* w0 = (const unsigned short*)Wsel + k*64 + cc;
            const unsigned short* w1 = (const unsigned short*)Wsel + (64+k)*64 + cc;
            a0 += a*bf2f(w0[0]) + r*bf2f(w1[0]);
            a1 += a*bf2f(w0[1]) + r*bf2f(w1[1]);
            a2 += a*bf2f(w0[2]) + r*bf2f(w1[2]);
            a3 += a*bf2f(w0[3]) + r*bf2f(w1[3]);
            a4 += a*bf2f(w0[4]) + r*bf2f(w1[4]);
            a5 += a*bf2f(w0[5]) + r*bf2f(w1[5]);
            a6 += a*bf2f(w0[6]) + r*bf2f(w1[6]);
            a7 += a*bf2f(w0[7]) + r*bf2f(w1[7]);
        }
    } else {
        const float* xf = (const float*)x;
        const float* Wf = (const float*)Wsel;
        for (int k = 0; k < 64; ++k){
            float a = xf[node*64 + k];
            float r = rs[node*64 + k];
            const float* w0 = Wf + k*64 + cc;
            const float* w1 = Wf + (64+k)*64 + cc;
            a0 += a*w0[0] + r*w1[0];
            a1 += a*w0[1] + r*w1[1];
            a2 += a*w0[2] + r*w1[2];
            a3 += a*w0[3] + r*w1[3];
            a4 += a*w0[4] + r*w1[4];
            a5 += a*w0[5] + r*w1[5];
            a6 += a*w0[6] + r*w1[6];
            a7 += a*w0[7] + r*w1[7];
        }
    }
    unsigned short* o = X1b + node*128 + c0;
    o[0]=f2bf(a0); o[1]=f2bf(a1); o[2]=f2bf(a2); o[3]=f2bf(a3);
    o[4]=f2bf(a4); o[5]=f2bf(a5); o[6]=f2bf(a6); o[7]=f2bf(a7);
}

// edge gather: bf16 X1, 2 cols/thread via one u32 load, 32 threads/edge.
__global__ void k_gather_e2(const int* indptr_e, const int* Bc, const int* elist,
                            const unsigned short* X1b, const void* hw,
                            const float* Binv, float* m, int pairBase, int C,
                            const int* flag){
    int bf = *flag;
    int t = blockIdx.x*256 + threadIdx.x;
    if (t >= N_EDGES*32) return;
    int e = t >> 5, p = t & 31;
    int cp = pairBase + p;
    int beg = indptr_e[e], cnt = Bc[e];
    float acc0 = 0.f, acc1 = 0.f;
    for (int j = 0; j < cnt; ++j){
        int n = elist[beg + j];
        unsigned v = *(const unsigned*)(X1b + n*128 + cp*2);
        acc0 += bf2f((unsigned short)(v & 0xFFFFu));
        acc1 += bf2f((unsigned short)(v >> 16));
    }
    float wsc = ldv(hw, e, bf) * Binv[e];
    m[e*C + cp*2]     = acc0 * wsc;
    m[e*C + cp*2 + 1] = acc1 * wsc;
}

// fused node gather + gate prep: thread per (node, col 0..127), fully coalesced.
// v = relu(base + Dinv*conv + gb[c]) written to P (gate pre-activations).
__global__ void k_gather_prep_gate(const int* indptr_n, const int* Dc,
                                   const int* nlist, const float* m,
                                   const void* x, const void* st,
                                   const float* Dinv, const void* gb,
                                   float* P, const int* flag){
    int bf = *flag;
    int t = blockIdx.x*256 + threadIdx.x;
    if (t >= N_NODES*128) return;
    int n = t >> 7, c = t & 127;
    int beg = indptr_n[n], cnt = Dc[n];
    float acc = 0.f;
    for (int j = 0; j < cnt; ++j){
        int e = nlist[beg + j];
        acc += m[e*128 + c];
    }
    float base = (c < 64) ? ldv(x, n*64 + c, bf) : ldv(st, n*64 + c - 64, bf);
    float v = base + Dinv[n]*acc + ldv(gb, c, bf);
    if (v < 0.f) v = 0.f;
    P[t] = v;
}

// fused node gather + cand prep: thread per (node, col 0..63), coalesced.
__global__ void k_gather_prep_cand(const int* indptr_n, const int* Dc,
                                   const int* nlist, const float* m,
                                   const unsigned short* X1b, const float* Dinv,
                                   const void* cbv, const void* crb,
                                   float* P2, const int* flag){
    int bf = *flag;
    int t = blockIdx.x*256 + threadIdx.x;
    if (t >= N_NODES*64) return;
    int n = t >> 6, c = t & 63;
    int beg = indptr_n[n], cnt = Dc[n];
    float acc = 0.f;
    for (int j = 0; j < cnt; ++j){
        int e = nlist[beg + j];
        acc += m[e*64 + c];
    }
    float v = bf2f(X1b[n*128 + 64 + c]) + ldv(crb, c, bf)
            + Dinv[n]*acc + ldv(cbv, c, bf);
    if (v < 0.f) v = 0.f;
    P2[t] = v;
}

// row stats: thread per node, 64-thread blocks (block footprint = 64 rows
// = 32 KB for C=128 -> fits L1, read-only, each line fetched once).
__global__ void k_stat(const float* P, float* pstat, int nrows, int C){
    int n = blockIdx.x*64 + threadIdx.x;
    if (n >= nrows) return;
    float s = 0.f, sq = 0.f;
    for (int c = 0; c < C; ++c){
        float v = P[n*C + c];
        s += v; sq += v*v;
    }
    pstat[n*2]     = s;
    pstat[n*2 + 1] = sq;
}

// gate fin: thread per (node, col<64).
__global__ void k_gate_fin2(const void* st, const float* P, const float* pstat,
                            const void* lng, const void* lnb,
                            float* zbuf, float* rs, const int* flag){
    int bf = *flag;
    int t = blockIdx.x*256 + threadIdx.x;
    if (t >= N_NODES*64) return;
    int n = t >> 6, c = t & 63;
    float s  = pstat[2*n];
    float sq = pstat[2*n + 1];
    float mu = s * (1.f/128.f);
    float var = sq * (1.f/128.f) - mu*mu;
    if (var < 0.f) var = 0.f;
    float inv = 1.f / sqrtf(var + 1e-5f);
    float v0 = P[n*128 + c];
    float v1 = P[n*128 + 64 + c];
    float u0 = (v0 - mu)*inv*ldv(lng, c, bf)      + ldv(lnb, c, bf);
    float u1 = (v1 - mu)*inv*ldv(lng, 64 + c, bf) + ldv(lnb, 64 + c, bf);
    float z = 1.f/(1.f + expf(-u0));
    float r = 1.f/(1.f + expf(-u1));
    float s1 = ldv(st, t, bf);
    zbuf[t] = z;
    rs[t]   = r * s1;
}

// cand fin: thread per (node, col). LN + tanh + GRU blend -> out.
__global__ void k_cand_fin2(const void* st, const float* P2, const float* pstat,
                            const void* lng, const void* lnb, const float* zbuf,
                            void* out, const int* flag){
    int bf = *flag;
    int t = blockIdx.x*256 + threadIdx.x;
    if (t >= N_NODES*64) return;
    int n = t >> 6, c = t & 63;
    float s  = pstat[2*n];
    float sq = pstat[2*n + 1];
    float mu = s * (1.f/64.f);
    float var = sq * (1.f/64.f) - mu*mu;
    if (var < 0.f) var = 0.f;
    float inv = 1.f / sqrtf(var + 1e-5f);
    float v = P2[t];
    float u = (v - mu)*inv*ldv(lng, c, bf) + ldv(lnb, c, bf);
    float hc = tanhf(u);
    float z = zbuf[t];
    float sv = ldv(st, t, bf);
    float res = (1.f - z)*sv + z*hc;
    if (bf) ((unsigned short*)out)[t] = f2bf(res);
    else    ((float*)out)[t] = res;
}

extern "C" void kernel_launch(void* const* d_in, const int* in_sizes, int n_in,
                              void* d_out, int out_size, void* d_ws, size_t ws_size,
                              hipStream_t stream){
    const void* x      = d_in[0];
    const void* state  = d_in[1];
    const int*  hidx   = (const int*)d_in[2];
    const void* hw     = d_in[3];
    const void* gate_W = d_in[4];
    const void* gate_b = d_in[5];
    const void* glng   = d_in[6];
    const void* glnb   = d_in[7];
    const void* cand_W = d_in[8];
    const void* cand_b = d_in[9];
    const void* clng   = d_in[10];
    const void* clnb   = d_in[11];
    const void* crW    = d_in[12];
    const void* crb    = d_in[13];
    (void)in_sizes; (void)n_in; (void)ws_size;

    const int* nidx = hidx;
    const int* eidx = hidx + N_INC;

    const int NCH_N = (N_NODES + 127)/128;   // 391
    const int NCH_E = (N_EDGES + 127)/128;   // 79

    // ---- workspace (byte offsets, 256B-aligned, total ~77.7 MB) ----
    char* w = (char*)d_ws;
    int*   flag     = (int*)  (w);
    float* D        = (float*)(w + 256);        // 50048 f  (-> Dinv)
    int*   Bc       = (int*)  (w + 200448);     // 10048 i
    int*   Dc       = (int*)  (w + 240640);     // 50048 i   (D,Bc,Dc contiguous: zeroed)
    float* Binv     = (float*)(w + 440832);     // 10048 f
    int*   indptr_n = (int*)  (w + 481024);     // 50048 i
    int*   cursor_n = (int*)  (w + 681216);     // 50048 i
    int*   indptr_e = (int*)  (w + 881408);     // 10048 i
    int*   cursor_e = (int*)  (w + 921600);     // 10048 i
    int*   csum_n   = (int*)  (w + 961792);     // 512 i
    int*   cbase_n  = (int*)  (w + 963840);     // 512 i
    int*   csum_e   = (int*)  (w + 965888);     // 256 i
    int*   cbase_e  = (int*)  (w + 966912);     // 256 i
    int*   nlist    = (int*)  (w + 967936);     // 800000 i
    int*   elist    = (int*)  (w + 4167936);    // 800000 i
    float* m        = (float*)(w + 7367936);    // 10000*128 f
    unsigned short* X1b = (unsigned short*)(w + 12487936);  // 50000*128 u16
    float* P        = (float*)(w + 25287936);   // 50000*128 f (gate P; cand P2 aliases)
    float* P2       = P;                        // cand P (gate P dead by then)
    float* zbuf     = (float*)(w + 50887936);   // 50000*64 f
    float* rs       = (float*)(w + 63687936);   // 50000*64 f
    float* pstat_g  = (float*)(w + 76487936);   // 100000 f
    float* pstat_c  = (float*)(w + 77287936);   // 100000 f -> ends 77687936

    // dtype detect + sentinel
    k_detect<<<1, 64, 0, stream>>>((const unsigned short*)hw, flag);
    k_sent<<<(out_size + 255)/256, 256, 0, stream>>>((unsigned short*)d_out, out_size);

    // zero D,Bc,Dc (contiguous 110144 words)
    k_zero<<<(110144 + 255)/256, 256, 0, stream>>>(D, 110144);

    // degrees + CSR build
    k_count<<<(N_INC + 255)/256, 256, 0, stream>>>(nidx, eidx, hw, D, Dc, Bc, flag);
    k_invert<<<(N_NODES + 255)/256, 256, 0, stream>>>(D, Bc, Binv);
    k_chunksum<<<(NCH_N + 255)/256, 256, 0, stream>>>(Dc, csum_n, N_NODES, NCH_N);
    k_chunkscan<<<1, 64, 0, stream>>>(csum_n, cbase_n, NCH_N);
    k_chunkfill<<<(NCH_N + 255)/256, 256, 0, stream>>>(Dc, cbase_n, indptr_n, cursor_n,
                                                       N_NODES, NCH_N);
    k_chunksum<<<(NCH_E + 255)/256, 256, 0, stream>>>(Bc, csum_e, N_EDGES, NCH_E);
    k_chunkscan<<<1, 64, 0, stream>>>(csum_e, cbase_e, NCH_E);
    k_chunkfill<<<(NCH_E + 255)/256, 256, 0, stream>>>(Bc, cbase_e, indptr_e, cursor_e,
                                                       N_EDGES, NCH_E);
    k_fill<<<(N_INC + 255)/256, 256, 0, stream>>>(nidx, eidx, cursor_n, nlist,
                                                  cursor_e, elist);

    // ---- gate path ----
    k_gemm_gate<<<N_NODES/16, 256, 0, stream>>>(x, state, gate_W, X1b, flag);
    k_gather_e2<<<(N_EDGES*32 + 255)/256, 256, 0, stream>>>(indptr_e, Bc, elist, X1b,
                                                            hw, Binv, m, 0, 128, flag);
    k_gather_e2<<<(N_EDGES*32 + 255)/256, 256, 0, stream>>>(indptr_e, Bc, elist, X1b,
                                                            hw, Binv, m, 32, 128, flag);
    k_gather_prep_gate<<<(N_NODES*128 + 255)/256, 256, 0, stream>>>(indptr_n, Dc, nlist,
                                                                    m, x, state, D,
                                                                    gate_b, P, flag);
    k_stat<<<(N_NODES + 63)/64, 64, 0, stream>>>(P, pstat_g, N_NODES, 128);
    k_gate_fin2<<<(N_NODES*64 + 255)/256, 256, 0, stream>>>(state, P, pstat_g,
                                                            glng, glnb, zbuf, rs, flag);

    // ---- candidate path ----
    k_gemm_cand<<<N_NODES/16, 256, 0, stream>>>(x, rs, cand_W, crW, X1b, flag);
    k_gather_e2<<<(N_EDGES*32 + 255)/256, 256, 0, stream>>>(indptr_e, Bc, elist, X1b,
                                                            hw, Binv, m, 0, 64, flag);
    k_gather_prep_cand<<<(N_NODES*64 + 255)/256, 256, 0, stream>>>(indptr_n, Dc, nlist,
                                                                   m, X1b, D, cand_b,
                                                                   crb, P2, flag);
    k_stat<<<(N_NODES + 63)/64, 64, 0, stream>>>(P2, pstat_c, N_NODES, 64);
    k_cand_fin2<<<(N_NODES*64 + 255)/256, 256, 0, stream>>>(state, P2, pstat_c,
                                                            clng, clnb, zbuf,
                                                            d_out, flag);
}

// Round 15
// 1114.919 us; speedup vs baseline: 2.0255x; 1.0146x over previous
//
#include <hip/hip_runtime.h>

#define N_NODES 50000
#define N_EDGES 10000
#define N_INC   800000
// IN_F=64, HID=64, concat width 128.
// Input dtype (f32 vs raw-bf16) detected on device (k_detect) — f32 confirmed in R8.
// X1 AND m intermediates stored bf16: m (gate 2.56 MB) fits per-XCD L2 entirely.

__device__ float bf2f(unsigned short u){
    return __uint_as_float(((unsigned)u) << 16);
}
__device__ unsigned short f2bf(float f){
    unsigned u = __float_as_uint(f);
    unsigned r = u + 0x7FFFu + ((u >> 16) & 1u);
    return (unsigned short)(r >> 16);
}
__device__ float ldv(const void* p, int i, int bf){
    if (bf) return bf2f(((const unsigned short*)p)[i]);
    return ((const float*)p)[i];
}

__global__ void k_detect(const unsigned short* hw, int* flag){
    if (blockIdx.x == 0 && threadIdx.x == 0){
        int ok = 1;
        for (int j = 0; j < 64; ++j){
            float v = bf2f(hw[j]);
            if (!(v > 0.05f && v < 1.2f)) ok = 0;
        }
        *flag = ok;
    }
}

__global__ void k_sent(unsigned short* p, int n){
    int i = blockIdx.x*256 + threadIdx.x;
    if (i < n) p[i] = 0x4204;
}

__global__ void k_zero(float* p, int n){
    int i = blockIdx.x*256 + threadIdx.x;
    if (i < n) p[i] = 0.f;
}

// counts: weighted node degree D, node degree Dc, edge cardinality Bc
__global__ void k_count(const int* nidx, const int* eidx, const void* hw,
                        float* D, int* Dc, int* Bc, const int* flag){
    int bf = *flag;
    int i = blockIdx.x*256 + threadIdx.x;
    if (i < N_INC){
        atomicAdd(&D[nidx[i]], ldv(hw, eidx[i], bf));
        atomicAdd(&Dc[nidx[i]], 1);
        atomicAdd(&Bc[eidx[i]], 1);
    }
}

__global__ void k_invert(float* D, const int* Bc, float* Binv){
    int i = blockIdx.x*256 + threadIdx.x;
    if (i < N_NODES) D[i] = D[i] > 0.f ? 1.f/D[i] : 0.f;      // becomes Dinv
    if (i < N_EDGES) Binv[i] = Bc[i] > 0 ? 1.f/(float)Bc[i] : 0.f;
}

// ---- chunked exclusive scan, no LDS ----
__global__ void k_chunksum(const int* cnt, int* csum, int n, int nchunks){
    int ch = blockIdx.x*256 + threadIdx.x;
    if (ch >= nchunks) return;
    int beg = ch*128, end = beg + 128;
    if (end > n) end = n;
    int s = 0;
    for (int i = beg; i < end; ++i) s += cnt[i];
    csum[ch] = s;
}
__global__ void k_chunkscan(const int* csum, int* cbase, int nchunks){
    if (blockIdx.x == 0 && threadIdx.x == 0){
        int run = 0;
        for (int ch = 0; ch < nchunks; ++ch){
            cbase[ch] = run;
            run += csum[ch];
        }
    }
}
__global__ void k_chunkfill(const int* cnt, const int* cbase, int* indptr,
                            int* cursor, int n, int nchunks){
    int ch = blockIdx.x*256 + threadIdx.x;
    if (ch >= nchunks) return;
    int beg = ch*128, end = beg + 128;
    if (end > n) end = n;
    int run = cbase[ch];
    for (int i = beg; i < end; ++i){
        indptr[i] = run;
        cursor[i] = run;
        run += cnt[i];
    }
}

__global__ void k_fill(const int* nidx, const int* eidx,
                       int* cursor_n, int* nlist,
                       int* cursor_e, int* elist){
    int i = blockIdx.x*256 + threadIdx.x;
    if (i < N_INC){
        int pn = atomicAdd(&cursor_n[nidx[i]], 1);
        nlist[pn] = eidx[i];
        int pe = atomicAdd(&cursor_e[eidx[i]], 1);
        elist[pe] = nidx[i];
    }
}

// gate GEMM: register-tiled, 8 outputs/thread, bf16 X1 out.
__global__ void k_gemm_gate(const void* x, const void* st, const void* W,
                            unsigned short* X1b, const int* flag){
    int bf = *flag;
    int tid = threadIdx.x;
    int node = blockIdx.x*16 + (tid >> 4);
    int c0 = (tid & 15) * 8;
    if (node >= N_NODES) return;
    float a0=0.f,a1=0.f,a2=0.f,a3=0.f,a4=0.f,a5=0.f,a6=0.f,a7=0.f;
    if (bf){
        for (int k = 0; k < 64; ++k){
            float a = ldv(x, node*64 + k, 1);
            float b = ldv(st, node*64 + k, 1);
            const unsigned short* w0 = (const unsigned short*)W + k*128 + c0;
            const unsigned short* w1 = (const unsigned short*)W + (64+k)*128 + c0;
            a0 += a*bf2f(w0[0]) + b*bf2f(w1[0]);
            a1 += a*bf2f(w0[1]) + b*bf2f(w1[1]);
            a2 += a*bf2f(w0[2]) + b*bf2f(w1[2]);
            a3 += a*bf2f(w0[3]) + b*bf2f(w1[3]);
            a4 += a*bf2f(w0[4]) + b*bf2f(w1[4]);
            a5 += a*bf2f(w0[5]) + b*bf2f(w1[5]);
            a6 += a*bf2f(w0[6]) + b*bf2f(w1[6]);
            a7 += a*bf2f(w0[7]) + b*bf2f(w1[7]);
        }
    } else {
        const float* xf = (const float*)x;
        const float* sf = (const float*)st;
        const float* Wf = (const float*)W;
        for (int k = 0; k < 64; ++k){
            float a = xf[node*64 + k];
            float b = sf[node*64 + k];
            const float* w0 = Wf + k*128 + c0;
            const float* w1 = Wf + (64+k)*128 + c0;
            a0 += a*w0[0] + b*w1[0];
            a1 += a*w0[1] + b*w1[1];
            a2 += a*w0[2] + b*w1[2];
            a3 += a*w0[3] + b*w1[3];
            a4 += a*w0[4] + b*w1[4];
            a5 += a*w0[5] + b*w1[5];
            a6 += a*w0[6] + b*w1[6];
            a7 += a*w0[7] + b*w1[7];
        }
    }
    unsigned short* o = X1b + node*128 + c0;
    o[0]=f2bf(a0); o[1]=f2bf(a1); o[2]=f2bf(a2); o[3]=f2bf(a3);
    o[4]=f2bf(a4); o[5]=f2bf(a5); o[6]=f2bf(a6); o[7]=f2bf(a7);
}

// cand GEMM: cols 0-63 from Wc, 64-127 from Wr; bf16 X1 out.
__global__ void k_gemm_cand(const void* x, const float* rs, const void* Wc,
                            const void* Wr, unsigned short* X1b, const int* flag){
    int bf = *flag;
    int tid = threadIdx.x;
    int node = blockIdx.x*16 + (tid >> 4);
    int cq = tid & 15;
    int c0 = cq * 8;
    int cc = c0 & 63;
    if (node >= N_NODES) return;
    const void* Wsel = (cq < 8) ? Wc : Wr;
    float a0=0.f,a1=0.f,a2=0.f,a3=0.f,a4=0.f,a5=0.f,a6=0.f,a7=0.f;
    if (bf){
        for (int k = 0; k < 64; ++k){
            float a = ldv(x, node*64 + k, 1);
            float r = rs[node*64 + k];
            const unsigned short* w0 = (const unsigned short*)Wsel + k*64 + cc;
            const unsigned short* w1 = (const unsigned short*)Wsel + (64+k)*64 + cc;
            a0 += a*bf2f(w0[0]) + r*bf2f(w1[0]);
            a1 += a*bf2f(w0[1]) + r*bf2f(w1[1]);
            a2 += a*bf2f(w0[2]) + r*bf2f(w1[2]);
            a3 += a*bf2f(w0[3]) + r*bf2f(w1[3]);
            a4 += a*bf2f(w0[4]) + r*bf2f(w1[4]);
            a5 += a*bf2f(w0[5]) + r*bf2f(w1[5]);
            a6 += a*bf2f(w0[6]) + r*bf2f(w1[6]);
            a7 += a*bf2f(w0[7]) + r*bf2f(w1[7]);
        }
    } else {
        const float* xf = (const float*)x;
        const float* Wf = (const float*)Wsel;
        for (int k = 0; k < 64; ++k){
            float a = xf[node*64 + k];
            float r = rs[node*64 + k];
            const float* w0 = Wf + k*64 + cc;
            const float* w1 = Wf + (64+k)*64 + cc;
            a0 += a*w0[0] + r*w1[0];
            a1 += a*w0[1] + r*w1[1];
            a2 += a*w0[2] + r*w1[2];
            a3 += a*w0[3] + r*w1[3];
            a4 += a*w0[4] + r*w1[4];
            a5 += a*w0[5] + r*w1[5];
            a6 += a*w0[6] + r*w1[6];
            a7 += a*w0[7] + r*w1[7];
        }
    }
    unsigned short* o = X1b + node*128 + c0;
    o[0]=f2bf(a0); o[1]=f2bf(a1); o[2]=f2bf(a2); o[3]=f2bf(a3);
    o[4]=f2bf(a4); o[5]=f2bf(a5); o[6]=f2bf(a6); o[7]=f2bf(a7);
}

// edge gather: bf16 X1 in, bf16 m out (packed u32 pair store). 32 threads/edge.
__global__ void k_gather_e2(const int* indptr_e, const int* Bc, const int* elist,
                            const unsigned short* X1b, const void* hw,
                            const float* Binv, unsigned* mb, int pairBase, int CP,
                            const int* flag){
    int bf = *flag;
    int t = blockIdx.x*256 + threadIdx.x;
    if (t >= N_EDGES*32) return;
    int e = t >> 5, p = t & 31;
    int cp = pairBase + p;
    int beg = indptr_e[e], cnt = Bc[e];
    float acc0 = 0.f, acc1 = 0.f;
    for (int j = 0; j < cnt; ++j){
        int n = elist[beg + j];
        unsigned v = *(const unsigned*)(X1b + n*128 + cp*2);
        acc0 += bf2f((unsigned short)(v & 0xFFFFu));
        acc1 += bf2f((unsigned short)(v >> 16));
    }
    float wsc = ldv(hw, e, bf) * Binv[e];
    unsigned lo = f2bf(acc0 * wsc);
    unsigned hi = f2bf(acc1 * wsc);
    mb[e*CP + cp] = lo | (hi << 16);     // CP = C/2 pairs per edge
}

// fused node gather + gate prep: thread per (node, col 0..127); m bf16.
__global__ void k_gather_prep_gate(const int* indptr_n, const int* Dc,
                                   const int* nlist, const unsigned short* mb,
                                   const void* x, const void* st,
                                   const float* Dinv, const void* gb,
                                   float* P, const int* flag){
    int bf = *flag;
    int t = blockIdx.x*256 + threadIdx.x;
    if (t >= N_NODES*128) return;
    int n = t >> 7, c = t & 127;
    int beg = indptr_n[n], cnt = Dc[n];
    float acc = 0.f;
    for (int j = 0; j < cnt; ++j){
        int e = nlist[beg + j];
        acc += bf2f(mb[e*128 + c]);
    }
    float base = (c < 64) ? ldv(x, n*64 + c, bf) : ldv(st, n*64 + c - 64, bf);
    float v = base + Dinv[n]*acc + ldv(gb, c, bf);
    if (v < 0.f) v = 0.f;
    P[t] = v;
}

// fused node gather + cand prep: thread per (node, col 0..63); m bf16.
__global__ void k_gather_prep_cand(const int* indptr_n, const int* Dc,
                                   const int* nlist, const unsigned short* mb,
                                   const unsigned short* X1b, const float* Dinv,
                                   const void* cbv, const void* crb,
                                   float* P2, const int* flag){
    int bf = *flag;
    int t = blockIdx.x*256 + threadIdx.x;
    if (t >= N_NODES*64) return;
    int n = t >> 6, c = t & 63;
    int beg = indptr_n[n], cnt = Dc[n];
    float acc = 0.f;
    for (int j = 0; j < cnt; ++j){
        int e = nlist[beg + j];
        acc += bf2f(mb[e*64 + c]);
    }
    float v = bf2f(X1b[n*128 + 64 + c]) + ldv(crb, c, bf)
            + Dinv[n]*acc + ldv(cbv, c, bf);
    if (v < 0.f) v = 0.f;
    P2[t] = v;
}

// row stats: thread per node, 64-thread blocks (block footprint fits L1).
__global__ void k_stat(const float* P, float* pstat, int nrows, int C){
    int n = blockIdx.x*64 + threadIdx.x;
    if (n >= nrows) return;
    float s = 0.f, sq = 0.f;
    for (int c = 0; c < C; ++c){
        float v = P[n*C + c];
        s += v; sq += v*v;
    }
    pstat[n*2]     = s;
    pstat[n*2 + 1] = sq;
}

// gate fin: thread per (node, col<64).
__global__ void k_gate_fin2(const void* st, const float* P, const float* pstat,
                            const void* lng, const void* lnb,
                            float* zbuf, float* rs, const int* flag){
    int bf = *flag;
    int t = blockIdx.x*256 + threadIdx.x;
    if (t >= N_NODES*64) return;
    int n = t >> 6, c = t & 63;
    float s  = pstat[2*n];
    float sq = pstat[2*n + 1];
    float mu = s * (1.f/128.f);
    float var = sq * (1.f/128.f) - mu*mu;
    if (var < 0.f) var = 0.f;
    float inv = 1.f / sqrtf(var + 1e-5f);
    float v0 = P[n*128 + c];
    float v1 = P[n*128 + 64 + c];
    float u0 = (v0 - mu)*inv*ldv(lng, c, bf)      + ldv(lnb, c, bf);
    float u1 = (v1 - mu)*inv*ldv(lng, 64 + c, bf) + ldv(lnb, 64 + c, bf);
    float z = 1.f/(1.f + expf(-u0));
    float r = 1.f/(1.f + expf(-u1));
    float s1 = ldv(st, t, bf);
    zbuf[t] = z;
    rs[t]   = r * s1;
}

// cand fin: thread per (node, col). LN + tanh + GRU blend -> out.
__global__ void k_cand_fin2(const void* st, const float* P2, const float* pstat,
                            const void* lng, const void* lnb, const float* zbuf,
                            void* out, const int* flag){
    int bf = *flag;
    int t = blockIdx.x*256 + threadIdx.x;
    if (t >= N_NODES*64) return;
    int n = t >> 6, c = t & 63;
    float s  = pstat[2*n];
    float sq = pstat[2*n + 1];
    float mu = s * (1.f/64.f);
    float var = sq * (1.f/64.f) - mu*mu;
    if (var < 0.f) var = 0.f;
    float inv = 1.f / sqrtf(var + 1e-5f);
    float v = P2[t];
    float u = (v - mu)*inv*ldv(lng, c, bf) + ldv(lnb, c, bf);
    float hc = tanhf(u);
    float z = zbuf[t];
    float sv = ldv(st, t, bf);
    float res = (1.f - z)*sv + z*hc;
    if (bf) ((unsigned short*)out)[t] = f2bf(res);
    else    ((float*)out)[t] = res;
}

extern "C" void kernel_launch(void* const* d_in, const int* in_sizes, int n_in,
                              void* d_out, int out_size, void* d_ws, size_t ws_size,
                              hipStream_t stream){
    const void* x      = d_in[0];
    const void* state  = d_in[1];
    const int*  hidx   = (const int*)d_in[2];
    const void* hw     = d_in[3];
    const void* gate_W = d_in[4];
    const void* gate_b = d_in[5];
    const void* glng   = d_in[6];
    const void* glnb   = d_in[7];
    const void* cand_W = d_in[8];
    const void* cand_b = d_in[9];
    const void* clng   = d_in[10];
    const void* clnb   = d_in[11];
    const void* crW    = d_in[12];
    const void* crb    = d_in[13];
    (void)in_sizes; (void)n_in; (void)ws_size;

    const int* nidx = hidx;
    const int* eidx = hidx + N_INC;

    const int NCH_N = (N_NODES + 127)/128;   // 391
    const int NCH_E = (N_EDGES + 127)/128;   // 79

    // ---- workspace (byte offsets, 256B-aligned, total ~75 MB) ----
    char* w = (char*)d_ws;
    int*   flag     = (int*)  (w);
    float* D        = (float*)(w + 256);        // 50048 f  (-> Dinv)
    int*   Bc       = (int*)  (w + 200448);     // 10048 i
    int*   Dc       = (int*)  (w + 240640);     // 50048 i   (D,Bc,Dc contiguous: zeroed)
    float* Binv     = (float*)(w + 440832);     // 10048 f
    int*   indptr_n = (int*)  (w + 481024);     // 50048 i
    int*   cursor_n = (int*)  (w + 681216);     // 50048 i
    int*   indptr_e = (int*)  (w + 881408);     // 10048 i
    int*   cursor_e = (int*)  (w + 921600);     // 10048 i
    int*   csum_n   = (int*)  (w + 961792);     // 512 i
    int*   cbase_n  = (int*)  (w + 963840);     // 512 i
    int*   csum_e   = (int*)  (w + 965888);     // 256 i
    int*   cbase_e  = (int*)  (w + 966912);     // 256 i
    int*   nlist    = (int*)  (w + 967936);     // 800000 i
    int*   elist    = (int*)  (w + 4167936);    // 800000 i
    unsigned* mb    = (unsigned*)(w + 7367936); // 10000*64 u32 (=128 bf16 cols)
    unsigned short* X1b = (unsigned short*)(w + 9927936);   // 50000*128 u16
    float* P        = (float*)(w + 22727936);   // 50000*128 f (gate P; cand P2 aliases)
    float* P2       = P;
    float* zbuf     = (float*)(w + 48327936);   // 50000*64 f
    float* rs       = (float*)(w + 61127936);   // 50000*64 f
    float* pstat_g  = (float*)(w + 73927936);   // 100000 f
    float* pstat_c  = (float*)(w + 74727936);   // 100000 f -> ends 75127936

    // dtype detect + sentinel
    k_detect<<<1, 64, 0, stream>>>((const unsigned short*)hw, flag);
    k_sent<<<(out_size + 255)/256, 256, 0, stream>>>((unsigned short*)d_out, out_size);

    // zero D,Bc,Dc (contiguous 110144 words)
    k_zero<<<(110144 + 255)/256, 256, 0, stream>>>(D, 110144);

    // degrees + CSR build
    k_count<<<(N_INC + 255)/256, 256, 0, stream>>>(nidx, eidx, hw, D, Dc, Bc, flag);
    k_invert<<<(N_NODES + 255)/256, 256, 0, stream>>>(D, Bc, Binv);
    k_chunksum<<<(NCH_N + 255)/256, 256, 0, stream>>>(Dc, csum_n, N_NODES, NCH_N);
    k_chunkscan<<<1, 64, 0, stream>>>(csum_n, cbase_n, NCH_N);
    k_chunkfill<<<(NCH_N + 255)/256, 256, 0, stream>>>(Dc, cbase_n, indptr_n, cursor_n,
                                                       N_NODES, NCH_N);
    k_chunksum<<<(NCH_E + 255)/256, 256, 0, stream>>>(Bc, csum_e, N_EDGES, NCH_E);
    k_chunkscan<<<1, 64, 0, stream>>>(csum_e, cbase_e, NCH_E);
    k_chunkfill<<<(NCH_E + 255)/256, 256, 0, stream>>>(Bc, cbase_e, indptr_e, cursor_e,
                                                       N_EDGES, NCH_E);
    k_fill<<<(N_INC + 255)/256, 256, 0, stream>>>(nidx, eidx, cursor_n, nlist,
                                                  cursor_e, elist);

    // ---- gate path ----
    k_gemm_gate<<<N_NODES/16, 256, 0, stream>>>(x, state, gate_W, X1b, flag);
    k_gather_e2<<<(N_EDGES*32 + 255)/256, 256, 0, stream>>>(indptr_e, Bc, elist, X1b,
                                                            hw, Binv, mb, 0, 64, flag);
    k_gather_e2<<<(N_EDGES*32 + 255)/256, 256, 0, stream>>>(indptr_e, Bc, elist, X1b,
                                                            hw, Binv, mb, 32, 64, flag);
    k_gather_prep_gate<<<(N_NODES*128 + 255)/256, 256, 0, stream>>>(indptr_n, Dc, nlist,
                                                                    (const unsigned short*)mb,
                                                                    x, state, D,
                                                                    gate_b, P, flag);
    k_stat<<<(N_NODES + 63)/64, 64, 0, stream>>>(P, pstat_g, N_NODES, 128);
    k_gate_fin2<<<(N_NODES*64 + 255)/256, 256, 0, stream>>>(state, P, pstat_g,
                                                            glng, glnb, zbuf, rs, flag);

    // ---- candidate path ----
    k_gemm_cand<<<N_NODES/16, 256, 0, stream>>>(x, rs, cand_W, crW, X1b, flag);
    k_gather_e2<<<(N_EDGES*32 + 255)/256, 256, 0, stream>>>(indptr_e, Bc, elist, X1b,
                                                            hw, Binv, mb, 0, 32, flag);
    k_gather_prep_cand<<<(N_NODES*64 + 255)/256, 256, 0, stream>>>(indptr_n, Dc, nlist,
                                                                   (const unsigned short*)mb,
                                                                   X1b, D, cand_b,
                                                                   crb, P2, flag);
    k_stat<<<(N_NODES + 63)/64, 64, 0, stream>>>(P2, pstat_c, N_NODES, 64);
    k_cand_fin2<<<(N_NODES*64 + 255)/256, 256, 0, stream>>>(state, P2, pstat_c,
                                                            clng, clnb, zbuf,
                                                            d_out, flag);
}

// Round 16
// 917.673 us; speedup vs baseline: 2.4609x; 1.2149x over previous
//
#include <hip/hip_runtime.h>

#define N_NODES 50000
#define N_EDGES 10000
#define N_INC   800000
// IN_F=64, HID=64, concat width 128.
// Input dtype (f32 vs raw-bf16) detected on device (k_detect) — f32 confirmed in R8.
// X1 AND m intermediates stored bf16. R16: register-tiled GEMMs (4 nodes x 8 cols),
// 4-col-blocked gather_prep kernels.

__device__ float bf2f(unsigned short u){
    return __uint_as_float(((unsigned)u) << 16);
}
__device__ unsigned short f2bf(float f){
    unsigned u = __float_as_uint(f);
    unsigned r = u + 0x7FFFu + ((u >> 16) & 1u);
    return (unsigned short)(r >> 16);
}
__device__ float ldv(const void* p, int i, int bf){
    if (bf) return bf2f(((const unsigned short*)p)[i]);
    return ((const float*)p)[i];
}

#define ACC8(A) float A##0=0.f,A##1=0.f,A##2=0.f,A##3=0.f,A##4=0.f,A##5=0.f,A##6=0.f,A##7=0.f
#define FMA8(A,a,b) A##0+=(a)*u0+(b)*v0; A##1+=(a)*u1+(b)*v1; A##2+=(a)*u2+(b)*v2; \
                    A##3+=(a)*u3+(b)*v3; A##4+=(a)*u4+(b)*v4; A##5+=(a)*u5+(b)*v5; \
                    A##6+=(a)*u6+(b)*v6; A##7+=(a)*u7+(b)*v7
#define STORE8(A,o) (o)[0]=f2bf(A##0);(o)[1]=f2bf(A##1);(o)[2]=f2bf(A##2);(o)[3]=f2bf(A##3); \
                    (o)[4]=f2bf(A##4);(o)[5]=f2bf(A##5);(o)[6]=f2bf(A##6);(o)[7]=f2bf(A##7)

__global__ void k_detect(const unsigned short* hw, int* flag){
    if (blockIdx.x == 0 && threadIdx.x == 0){
        int ok = 1;
        for (int j = 0; j < 64; ++j){
            float v = bf2f(hw[j]);
            if (!(v > 0.05f && v < 1.2f)) ok = 0;
        }
        *flag = ok;
    }
}

__global__ void k_sent(unsigned short* p, int n){
    int i = blockIdx.x*256 + threadIdx.x;
    if (i < n) p[i] = 0x4204;
}

__global__ void k_zero(float* p, int n){
    int i = blockIdx.x*256 + threadIdx.x;
    if (i < n) p[i] = 0.f;
}

// counts: weighted node degree D, node degree Dc, edge cardinality Bc
__global__ void k_count(const int* nidx, const int* eidx, const void* hw,
                        float* D, int* Dc, int* Bc, const int* flag){
    int bf = *flag;
    int i = blockIdx.x*256 + threadIdx.x;
    if (i < N_INC){
        atomicAdd(&D[nidx[i]], ldv(hw, eidx[i], bf));
        atomicAdd(&Dc[nidx[i]], 1);
        atomicAdd(&Bc[eidx[i]], 1);
    }
}

__global__ void k_invert(float* D, const int* Bc, float* Binv){
    int i = blockIdx.x*256 + threadIdx.x;
    if (i < N_NODES) D[i] = D[i] > 0.f ? 1.f/D[i] : 0.f;      // becomes Dinv
    if (i < N_EDGES) Binv[i] = Bc[i] > 0 ? 1.f/(float)Bc[i] : 0.f;
}

// ---- chunked exclusive scan, no LDS ----
__global__ void k_chunksum(const int* cnt, int* csum, int n, int nchunks){
    int ch = blockIdx.x*256 + threadIdx.x;
    if (ch >= nchunks) return;
    int beg = ch*128, end = beg + 128;
    if (end > n) end = n;
    int s = 0;
    for (int i = beg; i < end; ++i) s += cnt[i];
    csum[ch] = s;
}
__global__ void k_chunkscan(const int* csum, int* cbase, int nchunks){
    if (blockIdx.x == 0 && threadIdx.x == 0){
        int run = 0;
        for (int ch = 0; ch < nchunks; ++ch){
            cbase[ch] = run;
            run += csum[ch];
        }
    }
}
__global__ void k_chunkfill(const int* cnt, const int* cbase, int* indptr,
                            int* cursor, int n, int nchunks){
    int ch = blockIdx.x*256 + threadIdx.x;
    if (ch >= nchunks) return;
    int beg = ch*128, end = beg + 128;
    if (end > n) end = n;
    int run = cbase[ch];
    for (int i = beg; i < end; ++i){
        indptr[i] = run;
        cursor[i] = run;
        run += cnt[i];
    }
}

__global__ void k_fill(const int* nidx, const int* eidx,
                       int* cursor_n, int* nlist,
                       int* cursor_e, int* elist){
    int i = blockIdx.x*256 + threadIdx.x;
    if (i < N_INC){
        int pn = atomicAdd(&cursor_n[nidx[i]], 1);
        nlist[pn] = eidx[i];
        int pe = atomicAdd(&cursor_e[eidx[i]], 1);
        elist[pe] = nidx[i];
    }
}

// gate GEMM v3: 4 nodes x 8 cols per thread (block = 64 nodes x 128 cols).
// W regs reused across 4 nodes -> 4x less L1 traffic than v2.
__global__ void k_gemm_gate(const void* x, const void* st, const void* W,
                            unsigned short* X1b, const int* flag){
    int bf = *flag;
    int tid = threadIdx.x;
    int c0 = (tid & 15) * 8;
    int n0 = blockIdx.x*64 + (tid >> 4)*4;
    int g0 = n0 < N_NODES, g1 = n0+1 < N_NODES, g2 = n0+2 < N_NODES, g3 = n0+3 < N_NODES;
    ACC8(A); ACC8(B); ACC8(C); ACC8(D);
    int i0 = n0*64;
    if (bf){
        const unsigned short* Wh = (const unsigned short*)W;
        const unsigned short* xh = (const unsigned short*)x;
        const unsigned short* sh = (const unsigned short*)st;
        for (int k = 0; k < 64; ++k){
            const unsigned short* w0 = Wh + k*128 + c0;
            const unsigned short* w1 = w0 + 64*128;
            float u0=bf2f(w0[0]),u1=bf2f(w0[1]),u2=bf2f(w0[2]),u3=bf2f(w0[3]),
                  u4=bf2f(w0[4]),u5=bf2f(w0[5]),u6=bf2f(w0[6]),u7=bf2f(w0[7]);
            float v0=bf2f(w1[0]),v1=bf2f(w1[1]),v2=bf2f(w1[2]),v3=bf2f(w1[3]),
                  v4=bf2f(w1[4]),v5=bf2f(w1[5]),v6=bf2f(w1[6]),v7=bf2f(w1[7]);
            float a, b;
            a = g0?bf2f(xh[i0+k]):0.f;     b = g0?bf2f(sh[i0+k]):0.f;     FMA8(A,a,b);
            a = g1?bf2f(xh[i0+64+k]):0.f;  b = g1?bf2f(sh[i0+64+k]):0.f;  FMA8(B,a,b);
            a = g2?bf2f(xh[i0+128+k]):0.f; b = g2?bf2f(sh[i0+128+k]):0.f; FMA8(C,a,b);
            a = g3?bf2f(xh[i0+192+k]):0.f; b = g3?bf2f(sh[i0+192+k]):0.f; FMA8(D,a,b);
        }
    } else {
        const float* Wf = (const float*)W;
        const float* xf = (const float*)x;
        const float* sf = (const float*)st;
        for (int k = 0; k < 64; ++k){
            const float* w0 = Wf + k*128 + c0;
            const float* w1 = w0 + 64*128;
            float u0=w0[0],u1=w0[1],u2=w0[2],u3=w0[3],u4=w0[4],u5=w0[5],u6=w0[6],u7=w0[7];
            float v0=w1[0],v1=w1[1],v2=w1[2],v3=w1[3],v4=w1[4],v5=w1[5],v6=w1[6],v7=w1[7];
            float a, b;
            a = g0?xf[i0+k]:0.f;     b = g0?sf[i0+k]:0.f;     FMA8(A,a,b);
            a = g1?xf[i0+64+k]:0.f;  b = g1?sf[i0+64+k]:0.f;  FMA8(B,a,b);
            a = g2?xf[i0+128+k]:0.f; b = g2?sf[i0+128+k]:0.f; FMA8(C,a,b);
            a = g3?xf[i0+192+k]:0.f; b = g3?sf[i0+192+k]:0.f; FMA8(D,a,b);
        }
    }
    if (g0){ unsigned short* o = X1b + n0*128 + c0;       STORE8(A,o); }
    if (g1){ unsigned short* o = X1b + (n0+1)*128 + c0;   STORE8(B,o); }
    if (g2){ unsigned short* o = X1b + (n0+2)*128 + c0;   STORE8(C,o); }
    if (g3){ unsigned short* o = X1b + (n0+3)*128 + c0;   STORE8(D,o); }
}

// cand GEMM v3: same tiling; cols 0-63 from Wc, 64-127 from Wr; second operand rs (f32).
__global__ void k_gemm_cand(const void* x, const float* rs, const void* Wc,
                            const void* Wr, unsigned short* X1b, const int* flag){
    int bf = *flag;
    int tid = threadIdx.x;
    int cq = tid & 15;
    int c0 = cq * 8;
    int cc = c0 & 63;
    int n0 = blockIdx.x*64 + (tid >> 4)*4;
    int g0 = n0 < N_NODES, g1 = n0+1 < N_NODES, g2 = n0+2 < N_NODES, g3 = n0+3 < N_NODES;
    const void* Wsel = (cq < 8) ? Wc : Wr;
    ACC8(A); ACC8(B); ACC8(C); ACC8(D);
    int i0 = n0*64;
    if (bf){
        const unsigned short* Wh = (const unsigned short*)Wsel;
        const unsigned short* xh = (const unsigned short*)x;
        for (int k = 0; k < 64; ++k){
            const unsigned short* w0 = Wh + k*64 + cc;
            const unsigned short* w1 = w0 + 64*64;
            float u0=bf2f(w0[0]),u1=bf2f(w0[1]),u2=bf2f(w0[2]),u3=bf2f(w0[3]),
                  u4=bf2f(w0[4]),u5=bf2f(w0[5]),u6=bf2f(w0[6]),u7=bf2f(w0[7]);
            float v0=bf2f(w1[0]),v1=bf2f(w1[1]),v2=bf2f(w1[2]),v3=bf2f(w1[3]),
                  v4=bf2f(w1[4]),v5=bf2f(w1[5]),v6=bf2f(w1[6]),v7=bf2f(w1[7]);
            float a, b;
            a = g0?bf2f(xh[i0+k]):0.f;     b = g0?rs[i0+k]:0.f;     FMA8(A,a,b);
            a = g1?bf2f(xh[i0+64+k]):0.f;  b = g1?rs[i0+64+k]:0.f;  FMA8(B,a,b);
            a = g2?bf2f(xh[i0+128+k]):0.f; b = g2?rs[i0+128+k]:0.f; FMA8(C,a,b);
            a = g3?bf2f(xh[i0+192+k]):0.f; b = g3?rs[i0+192+k]:0.f; FMA8(D,a,b);
        }
    } else {
        const float* Wf = (const float*)Wsel;
        const float* xf = (const float*)x;
        for (int k = 0; k < 64; ++k){
            const float* w0 = Wf + k*64 + cc;
            const float* w1 = w0 + 64*64;
            float u0=w0[0],u1=w0[1],u2=w0[2],u3=w0[3],u4=w0[4],u5=w0[5],u6=w0[6],u7=w0[7];
            float v0=w1[0],v1=w1[1],v2=w1[2],v3=w1[3],v4=w1[4],v5=w1[5],v6=w1[6],v7=w1[7];
            float a, b;
            a = g0?xf[i0+k]:0.f;     b = g0?rs[i0+k]:0.f;     FMA8(A,a,b);
            a = g1?xf[i0+64+k]:0.f;  b = g1?rs[i0+64+k]:0.f;  FMA8(B,a,b);
            a = g2?xf[i0+128+k]:0.f; b = g2?rs[i0+128+k]:0.f; FMA8(C,a,b);
            a = g3?xf[i0+192+k]:0.f; b = g3?rs[i0+192+k]:0.f; FMA8(D,a,b);
        }
    }
    if (g0){ unsigned short* o = X1b + n0*128 + c0;       STORE8(A,o); }
    if (g1){ unsigned short* o = X1b + (n0+1)*128 + c0;   STORE8(B,o); }
    if (g2){ unsigned short* o = X1b + (n0+2)*128 + c0;   STORE8(C,o); }
    if (g3){ unsigned short* o = X1b + (n0+3)*128 + c0;   STORE8(D,o); }
}

// edge gather: bf16 X1 in, bf16 m out (packed u32 pair store). 32 threads/edge.
__global__ void k_gather_e2(const int* indptr_e, const int* Bc, const int* elist,
                            const unsigned short* X1b, const void* hw,
                            const float* Binv, unsigned* mb, int pairBase, int CP,
                            const int* flag){
    int bf = *flag;
    int t = blockIdx.x*256 + threadIdx.x;
    if (t >= N_EDGES*32) return;
    int e = t >> 5, p = t & 31;
    int cp = pairBase + p;
    int beg = indptr_e[e], cnt = Bc[e];
    float acc0 = 0.f, acc1 = 0.f;
    for (int j = 0; j < cnt; ++j){
        int n = elist[beg + j];
        unsigned v = *(const unsigned*)(X1b + n*128 + cp*2);
        acc0 += bf2f((unsigned short)(v & 0xFFFFu));
        acc1 += bf2f((unsigned short)(v >> 16));
    }
    float wsc = ldv(hw, e, bf) * Binv[e];
    unsigned lo = f2bf(acc0 * wsc);
    unsigned hi = f2bf(acc1 * wsc);
    mb[e*CP + cp] = lo | (hi << 16);     // CP = C/2 pairs per edge
}

// fused node gather + gate prep v2: thread per (node, 4-col group), m bf16.
__global__ void k_gather_prep_gate(const int* indptr_n, const int* Dc,
                                   const int* nlist, const unsigned* mb,
                                   const void* x, const void* st,
                                   const float* Dinv, const void* gb,
                                   float* P, const int* flag){
    int bf = *flag;
    int t = blockIdx.x*256 + threadIdx.x;
    if (t >= N_NODES*32) return;
    int n = t >> 5, g = t & 31;
    int c = g*4;
    int beg = indptr_n[n], cnt = Dc[n];
    float a0 = 0.f, a1 = 0.f, a2 = 0.f, a3 = 0.f;
    for (int j = 0; j < cnt; ++j){
        int e = nlist[beg + j];
        const unsigned* q = mb + e*64 + g*2;
        unsigned va = q[0], vb = q[1];
        a0 += bf2f((unsigned short)(va & 0xFFFFu));
        a1 += bf2f((unsigned short)(va >> 16));
        a2 += bf2f((unsigned short)(vb & 0xFFFFu));
        a3 += bf2f((unsigned short)(vb >> 16));
    }
    float di = Dinv[n];
    float b0, b1, b2, b3;
    if (c < 64){
        b0 = ldv(x, n*64 + c, bf);     b1 = ldv(x, n*64 + c + 1, bf);
        b2 = ldv(x, n*64 + c + 2, bf); b3 = ldv(x, n*64 + c + 3, bf);
    } else {
        int cc = c - 64;
        b0 = ldv(st, n*64 + cc, bf);     b1 = ldv(st, n*64 + cc + 1, bf);
        b2 = ldv(st, n*64 + cc + 2, bf); b3 = ldv(st, n*64 + cc + 3, bf);
    }
    float v0 = b0 + di*a0 + ldv(gb, c, bf);
    float v1 = b1 + di*a1 + ldv(gb, c + 1, bf);
    float v2 = b2 + di*a2 + ldv(gb, c + 2, bf);
    float v3 = b3 + di*a3 + ldv(gb, c + 3, bf);
    if (v0 < 0.f) v0 = 0.f;
    if (v1 < 0.f) v1 = 0.f;
    if (v2 < 0.f) v2 = 0.f;
    if (v3 < 0.f) v3 = 0.f;
    float* o = P + n*128 + c;
    o[0] = v0; o[1] = v1; o[2] = v2; o[3] = v3;
}

// fused node gather + cand prep v2: thread per (node, 4-col group), m bf16 (CP=32).
__global__ void k_gather_prep_cand(const int* indptr_n, const int* Dc,
                                   const int* nlist, const unsigned* mb,
                                   const unsigned short* X1b, const float* Dinv,
                                   const void* cbv, const void* crb,
                                   float* P2, const int* flag){
    int bf = *flag;
    int t = blockIdx.x*256 + threadIdx.x;
    if (t >= N_NODES*16) return;
    int n = t >> 4, g = t & 15;
    int c = g*4;
    int beg = indptr_n[n], cnt = Dc[n];
    float a0 = 0.f, a1 = 0.f, a2 = 0.f, a3 = 0.f;
    for (int j = 0; j < cnt; ++j){
        int e = nlist[beg + j];
        const unsigned* q = mb + e*32 + g*2;
        unsigned va = q[0], vb = q[1];
        a0 += bf2f((unsigned short)(va & 0xFFFFu));
        a1 += bf2f((unsigned short)(va >> 16));
        a2 += bf2f((unsigned short)(vb & 0xFFFFu));
        a3 += bf2f((unsigned short)(vb >> 16));
    }
    float di = Dinv[n];
    float v0 = bf2f(X1b[n*128 + 64 + c])     + ldv(crb, c, bf)     + di*a0 + ldv(cbv, c, bf);
    float v1 = bf2f(X1b[n*128 + 64 + c + 1]) + ldv(crb, c + 1, bf) + di*a1 + ldv(cbv, c + 1, bf);
    float v2 = bf2f(X1b[n*128 + 64 + c + 2]) + ldv(crb, c + 2, bf) + di*a2 + ldv(cbv, c + 2, bf);
    float v3 = bf2f(X1b[n*128 + 64 + c + 3]) + ldv(crb, c + 3, bf) + di*a3 + ldv(cbv, c + 3, bf);
    if (v0 < 0.f) v0 = 0.f;
    if (v1 < 0.f) v1 = 0.f;
    if (v2 < 0.f) v2 = 0.f;
    if (v3 < 0.f) v3 = 0.f;
    float* o = P2 + n*64 + c;
    o[0] = v0; o[1] = v1; o[2] = v2; o[3] = v3;
}

// row stats: thread per node, 64-thread blocks (block footprint fits L1).
__global__ void k_stat(const float* P, float* pstat, int nrows, int C){
    int n = blockIdx.x*64 + threadIdx.x;
    if (n >= nrows) return;
    float s = 0.f, sq = 0.f;
    for (int c = 0; c < C; ++c){
        float v = P[n*C + c];
        s += v; sq += v*v;
    }
    pstat[n*2]     = s;
    pstat[n*2 + 1] = sq;
}

// gate fin: thread per (node, col<64).
__global__ void k_gate_fin2(const void* st, const float* P, const float* pstat,
                            const void* lng, const void* lnb,
                            float* zbuf, float* rs, const int* flag){
    int bf = *flag;
    int t = blockIdx.x*256 + threadIdx.x;
    if (t >= N_NODES*64) return;
    int n = t >> 6, c = t & 63;
    float s  = pstat[2*n];
    float sq = pstat[2*n + 1];
    float mu = s * (1.f/128.f);
    float var = sq * (1.f/128.f) - mu*mu;
    if (var < 0.f) var = 0.f;
    float inv = 1.f / sqrtf(var + 1e-5f);
    float v0 = P[n*128 + c];
    float v1 = P[n*128 + 64 + c];
    float u0 = (v0 - mu)*inv*ldv(lng, c, bf)      + ldv(lnb, c, bf);
    float u1 = (v1 - mu)*inv*ldv(lng, 64 + c, bf) + ldv(lnb, 64 + c, bf);
    float z = 1.f/(1.f + expf(-u0));
    float r = 1.f/(1.f + expf(-u1));
    float s1 = ldv(st, t, bf);
    zbuf[t] = z;
    rs[t]   = r * s1;
}

// cand fin: thread per (node, col). LN + tanh + GRU blend -> out.
__global__ void k_cand_fin2(const void* st, const float* P2, const float* pstat,
                            const void* lng, const void* lnb, const float* zbuf,
                            void* out, const int* flag){
    int bf = *flag;
    int t = blockIdx.x*256 + threadIdx.x;
    if (t >= N_NODES*64) return;
    int n = t >> 6, c = t & 63;
    float s  = pstat[2*n];
    float sq = pstat[2*n + 1];
    float mu = s * (1.f/64.f);
    float var = sq * (1.f/64.f) - mu*mu;
    if (var < 0.f) var = 0.f;
    float inv = 1.f / sqrtf(var + 1e-5f);
    float v = P2[t];
    float u = (v - mu)*inv*ldv(lng, c, bf) + ldv(lnb, c, bf);
    float hc = tanhf(u);
    float z = zbuf[t];
    float sv = ldv(st, t, bf);
    float res = (1.f - z)*sv + z*hc;
    if (bf) ((unsigned short*)out)[t] = f2bf(res);
    else    ((float*)out)[t] = res;
}

extern "C" void kernel_launch(void* const* d_in, const int* in_sizes, int n_in,
                              void* d_out, int out_size, void* d_ws, size_t ws_size,
                              hipStream_t stream){
    const void* x      = d_in[0];
    const void* state  = d_in[1];
    const int*  hidx   = (const int*)d_in[2];
    const void* hw     = d_in[3];
    const void* gate_W = d_in[4];
    const void* gate_b = d_in[5];
    const void* glng   = d_in[6];
    const void* glnb   = d_in[7];
    const void* cand_W = d_in[8];
    const void* cand_b = d_in[9];
    const void* clng   = d_in[10];
    const void* clnb   = d_in[11];
    const void* crW    = d_in[12];
    const void* crb    = d_in[13];
    (void)in_sizes; (void)n_in; (void)ws_size;

    const int* nidx = hidx;
    const int* eidx = hidx + N_INC;

    const int NCH_N = (N_NODES + 127)/128;   // 391
    const int NCH_E = (N_EDGES + 127)/128;   // 79

    // ---- workspace (byte offsets, 256B-aligned, total ~75 MB) ----
    char* w = (char*)d_ws;
    int*   flag     = (int*)  (w);
    float* D        = (float*)(w + 256);        // 50048 f  (-> Dinv)
    int*   Bc       = (int*)  (w + 200448);     // 10048 i
    int*   Dc       = (int*)  (w + 240640);     // 50048 i   (D,Bc,Dc contiguous: zeroed)
    float* Binv     = (float*)(w + 440832);     // 10048 f
    int*   indptr_n = (int*)  (w + 481024);     // 50048 i
    int*   cursor_n = (int*)  (w + 681216);     // 50048 i
    int*   indptr_e = (int*)  (w + 881408);     // 10048 i
    int*   cursor_e = (int*)  (w + 921600);     // 10048 i
    int*   csum_n   = (int*)  (w + 961792);     // 512 i
    int*   cbase_n  = (int*)  (w + 963840);     // 512 i
    int*   csum_e   = (int*)  (w + 965888);     // 256 i
    int*   cbase_e  = (int*)  (w + 966912);     // 256 i
    int*   nlist    = (int*)  (w + 967936);     // 800000 i
    int*   elist    = (int*)  (w + 4167936);    // 800000 i
    unsigned* mb    = (unsigned*)(w + 7367936); // 10000*64 u32 (=128 bf16 cols)
    unsigned short* X1b = (unsigned short*)(w + 9927936);   // 50000*128 u16
    float* P        = (float*)(w + 22727936);   // 50000*128 f (gate P; cand P2 aliases)
    float* P2       = P;
    float* zbuf     = (float*)(w + 48327936);   // 50000*64 f
    float* rs       = (float*)(w + 61127936);   // 50000*64 f
    float* pstat_g  = (float*)(w + 73927936);   // 100000 f
    float* pstat_c  = (float*)(w + 74727936);   // 100000 f -> ends 75127936

    // dtype detect + sentinel
    k_detect<<<1, 64, 0, stream>>>((const unsigned short*)hw, flag);
    k_sent<<<(out_size + 255)/256, 256, 0, stream>>>((unsigned short*)d_out, out_size);

    // zero D,Bc,Dc (contiguous 110144 words)
    k_zero<<<(110144 + 255)/256, 256, 0, stream>>>(D, 110144);

    // degrees + CSR build
    k_count<<<(N_INC + 255)/256, 256, 0, stream>>>(nidx, eidx, hw, D, Dc, Bc, flag);
    k_invert<<<(N_NODES + 255)/256, 256, 0, stream>>>(D, Bc, Binv);
    k_chunksum<<<(NCH_N + 255)/256, 256, 0, stream>>>(Dc, csum_n, N_NODES, NCH_N);
    k_chunkscan<<<1, 64, 0, stream>>>(csum_n, cbase_n, NCH_N);
    k_chunkfill<<<(NCH_N + 255)/256, 256, 0, stream>>>(Dc, cbase_n, indptr_n, cursor_n,
                                                       N_NODES, NCH_N);
    k_chunksum<<<(NCH_E + 255)/256, 256, 0, stream>>>(Bc, csum_e, N_EDGES, NCH_E);
    k_chunkscan<<<1, 64, 0, stream>>>(csum_e, cbase_e, NCH_E);
    k_chunkfill<<<(NCH_E + 255)/256, 256, 0, stream>>>(Bc, cbase_e, indptr_e, cursor_e,
                                                       N_EDGES, NCH_E);
    k_fill<<<(N_INC + 255)/256, 256, 0, stream>>>(nidx, eidx, cursor_n, nlist,
                                                  cursor_e, elist);

    // ---- gate path ----
    k_gemm_gate<<<(N_NODES + 63)/64, 256, 0, stream>>>(x, state, gate_W, X1b, flag);
    k_gather_e2<<<(N_EDGES*32 + 255)/256, 256, 0, stream>>>(indptr_e, Bc, elist, X1b,
                                                            hw, Binv, mb, 0, 64, flag);
    k_gather_e2<<<(N_EDGES*32 + 255)/256, 256, 0, stream>>>(indptr_e, Bc, elist, X1b,
                                                            hw, Binv, mb, 32, 64, flag);
    k_gather_prep_gate<<<(N_NODES*32 + 255)/256, 256, 0, stream>>>(indptr_n, Dc, nlist,
                                                                   mb, x, state, D,
                                                                   gate_b, P, flag);
    k_stat<<<(N_NODES + 63)/64, 64, 0, stream>>>(P, pstat_g, N_NODES, 128);
    k_gate_fin2<<<(N_NODES*64 + 255)/256, 256, 0, stream>>>(state, P, pstat_g,
                                                            glng, glnb, zbuf, rs, flag);

    // ---- candidate path ----
    k_gemm_cand<<<(N_NODES + 63)/64, 256, 0, stream>>>(x, rs, cand_W, crW, X1b, flag);
    k_gather_e2<<<(N_EDGES*32 + 255)/256, 256, 0, stream>>>(indptr_e, Bc, elist, X1b,
                                                            hw, Binv, mb, 0, 32, flag);
    k_gather_prep_cand<<<(N_NODES*16 + 255)/256, 256, 0, stream>>>(indptr_n, Dc, nlist,
                                                                   mb, X1b, D, cand_b,
                                                                   crb, P2, flag);
    k_stat<<<(N_NODES + 63)/64, 64, 0, stream>>>(P2, pstat_c, N_NODES, 64);
    k_cand_fin2<<<(N_NODES*64 + 255)/256, 256, 0, stream>>>(state, P2, pstat_c,
                                                            clng, clnb, zbuf,
                                                            d_out, flag);
}

// Round 17
// 890.923 us; speedup vs baseline: 2.5348x; 1.0300x over previous
//
#include <hip/hip_runtime.h>

#define N_NODES 50000
#define N_EDGES 10000
#define N_INC   800000
// IN_F=64, HID=64, concat width 128.
// Input dtype (f32 vs raw-bf16) detected on device (k_detect) — f32 confirmed in R8.
// X1 AND m intermediates stored bf16. R17: k_count drops float-D atomic (D via CSR
// post-pass k_dinv), nlist stored u16, sentinel removed.

__device__ float bf2f(unsigned short u){
    return __uint_as_float(((unsigned)u) << 16);
}
__device__ unsigned short f2bf(float f){
    unsigned u = __float_as_uint(f);
    unsigned r = u + 0x7FFFu + ((u >> 16) & 1u);
    return (unsigned short)(r >> 16);
}
__device__ float ldv(const void* p, int i, int bf){
    if (bf) return bf2f(((const unsigned short*)p)[i]);
    return ((const float*)p)[i];
}

#define ACC8(A) float A##0=0.f,A##1=0.f,A##2=0.f,A##3=0.f,A##4=0.f,A##5=0.f,A##6=0.f,A##7=0.f
#define FMA8(A,a,b) A##0+=(a)*u0+(b)*v0; A##1+=(a)*u1+(b)*v1; A##2+=(a)*u2+(b)*v2; \
                    A##3+=(a)*u3+(b)*v3; A##4+=(a)*u4+(b)*v4; A##5+=(a)*u5+(b)*v5; \
                    A##6+=(a)*u6+(b)*v6; A##7+=(a)*u7+(b)*v7
#define STORE8(A,o) (o)[0]=f2bf(A##0);(o)[1]=f2bf(A##1);(o)[2]=f2bf(A##2);(o)[3]=f2bf(A##3); \
                    (o)[4]=f2bf(A##4);(o)[5]=f2bf(A##5);(o)[6]=f2bf(A##6);(o)[7]=f2bf(A##7)

__global__ void k_detect(const unsigned short* hw, int* flag){
    if (blockIdx.x == 0 && threadIdx.x == 0){
        int ok = 1;
        for (int j = 0; j < 64; ++j){
            float v = bf2f(hw[j]);
            if (!(v > 0.05f && v < 1.2f)) ok = 0;
        }
        *flag = ok;
    }
}

__global__ void k_zero(float* p, int n){
    int i = blockIdx.x*256 + threadIdx.x;
    if (i < n) p[i] = 0.f;
}

// counts: node degree Dc, edge cardinality Bc (int atomics only)
__global__ void k_count(const int* nidx, const int* eidx, int* Dc, int* Bc){
    int i = blockIdx.x*256 + threadIdx.x;
    if (i < N_INC){
        atomicAdd(&Dc[nidx[i]], 1);
        atomicAdd(&Bc[eidx[i]], 1);
    }
}

// Binv from Bc
__global__ void k_binv(const int* Bc, float* Binv){
    int i = blockIdx.x*256 + threadIdx.x;
    if (i < N_EDGES) Binv[i] = Bc[i] > 0 ? 1.f/(float)Bc[i] : 0.f;
}

// Dinv via CSR: D[n] = sum hw[e] over incident edges (nlist u16), then invert.
__global__ void k_dinv(const int* indptr_n, const int* Dc,
                       const unsigned short* nlist, const void* hw,
                       float* Dinv, const int* flag){
    int bf = *flag;
    int n = blockIdx.x*256 + threadIdx.x;
    if (n >= N_NODES) return;
    int beg = indptr_n[n], cnt = Dc[n];
    float s = 0.f;
    for (int j = 0; j < cnt; ++j){
        int e = nlist[beg + j];
        s += ldv(hw, e, bf);
    }
    Dinv[n] = s > 0.f ? 1.f/s : 0.f;
}

// ---- chunked exclusive scan, no LDS ----
__global__ void k_chunksum(const int* cnt, int* csum, int n, int nchunks){
    int ch = blockIdx.x*256 + threadIdx.x;
    if (ch >= nchunks) return;
    int beg = ch*128, end = beg + 128;
    if (end > n) end = n;
    int s = 0;
    for (int i = beg; i < end; ++i) s += cnt[i];
    csum[ch] = s;
}
__global__ void k_chunkscan(const int* csum, int* cbase, int nchunks){
    if (blockIdx.x == 0 && threadIdx.x == 0){
        int run = 0;
        for (int ch = 0; ch < nchunks; ++ch){
            cbase[ch] = run;
            run += csum[ch];
        }
    }
}
__global__ void k_chunkfill(const int* cnt, const int* cbase, int* indptr,
                            int* cursor, int n, int nchunks){
    int ch = blockIdx.x*256 + threadIdx.x;
    if (ch >= nchunks) return;
    int beg = ch*128, end = beg + 128;
    if (end > n) end = n;
    int run = cbase[ch];
    for (int i = beg; i < end; ++i){
        indptr[i] = run;
        cursor[i] = run;
        run += cnt[i];
    }
}

// fill both CSR lists: nlist u16 (edge ids < 10000), elist int
__global__ void k_fill(const int* nidx, const int* eidx,
                       int* cursor_n, unsigned short* nlist,
                       int* cursor_e, int* elist){
    int i = blockIdx.x*256 + threadIdx.x;
    if (i < N_INC){
        int pn = atomicAdd(&cursor_n[nidx[i]], 1);
        nlist[pn] = (unsigned short)eidx[i];
        int pe = atomicAdd(&cursor_e[eidx[i]], 1);
        elist[pe] = nidx[i];
    }
}

// gate GEMM v3: 4 nodes x 8 cols per thread (block = 64 nodes x 128 cols).
__global__ void k_gemm_gate(const void* x, const void* st, const void* W,
                            unsigned short* X1b, const int* flag){
    int bf = *flag;
    int tid = threadIdx.x;
    int c0 = (tid & 15) * 8;
    int n0 = blockIdx.x*64 + (tid >> 4)*4;
    int g0 = n0 < N_NODES, g1 = n0+1 < N_NODES, g2 = n0+2 < N_NODES, g3 = n0+3 < N_NODES;
    ACC8(A); ACC8(B); ACC8(C); ACC8(D);
    int i0 = n0*64;
    if (bf){
        const unsigned short* Wh = (const unsigned short*)W;
        const unsigned short* xh = (const unsigned short*)x;
        const unsigned short* sh = (const unsigned short*)st;
        for (int k = 0; k < 64; ++k){
            const unsigned short* w0 = Wh + k*128 + c0;
            const unsigned short* w1 = w0 + 64*128;
            float u0=bf2f(w0[0]),u1=bf2f(w0[1]),u2=bf2f(w0[2]),u3=bf2f(w0[3]),
                  u4=bf2f(w0[4]),u5=bf2f(w0[5]),u6=bf2f(w0[6]),u7=bf2f(w0[7]);
            float v0=bf2f(w1[0]),v1=bf2f(w1[1]),v2=bf2f(w1[2]),v3=bf2f(w1[3]),
                  v4=bf2f(w1[4]),v5=bf2f(w1[5]),v6=bf2f(w1[6]),v7=bf2f(w1[7]);
            float a, b;
            a = g0?bf2f(xh[i0+k]):0.f;     b = g0?bf2f(sh[i0+k]):0.f;     FMA8(A,a,b);
            a = g1?bf2f(xh[i0+64+k]):0.f;  b = g1?bf2f(sh[i0+64+k]):0.f;  FMA8(B,a,b);
            a = g2?bf2f(xh[i0+128+k]):0.f; b = g2?bf2f(sh[i0+128+k]):0.f; FMA8(C,a,b);
            a = g3?bf2f(xh[i0+192+k]):0.f; b = g3?bf2f(sh[i0+192+k]):0.f; FMA8(D,a,b);
        }
    } else {
        const float* Wf = (const float*)W;
        const float* xf = (const float*)x;
        const float* sf = (const float*)st;
        for (int k = 0; k < 64; ++k){
            const float* w0 = Wf + k*128 + c0;
            const float* w1 = w0 + 64*128;
            float u0=w0[0],u1=w0[1],u2=w0[2],u3=w0[3],u4=w0[4],u5=w0[5],u6=w0[6],u7=w0[7];
            float v0=w1[0],v1=w1[1],v2=w1[2],v3=w1[3],v4=w1[4],v5=w1[5],v6=w1[6],v7=w1[7];
            float a, b;
            a = g0?xf[i0+k]:0.f;     b = g0?sf[i0+k]:0.f;     FMA8(A,a,b);
            a = g1?xf[i0+64+k]:0.f;  b = g1?sf[i0+64+k]:0.f;  FMA8(B,a,b);
            a = g2?xf[i0+128+k]:0.f; b = g2?sf[i0+128+k]:0.f; FMA8(C,a,b);
            a = g3?xf[i0+192+k]:0.f; b = g3?sf[i0+192+k]:0.f; FMA8(D,a,b);
        }
    }
    if (g0){ unsigned short* o = X1b + n0*128 + c0;       STORE8(A,o); }
    if (g1){ unsigned short* o = X1b + (n0+1)*128 + c0;   STORE8(B,o); }
    if (g2){ unsigned short* o = X1b + (n0+2)*128 + c0;   STORE8(C,o); }
    if (g3){ unsigned short* o = X1b + (n0+3)*128 + c0;   STORE8(D,o); }
}

// cand GEMM v3: same tiling; cols 0-63 from Wc, 64-127 from Wr; second operand rs (f32).
__global__ void k_gemm_cand(const void* x, const float* rs, const void* Wc,
                            const void* Wr, unsigned short* X1b, const int* flag){
    int bf = *flag;
    int tid = threadIdx.x;
    int cq = tid & 15;
    int c0 = cq * 8;
    int cc = c0 & 63;
    int n0 = blockIdx.x*64 + (tid >> 4)*4;
    int g0 = n0 < N_NODES, g1 = n0+1 < N_NODES, g2 = n0+2 < N_NODES, g3 = n0+3 < N_NODES;
    const void* Wsel = (cq < 8) ? Wc : Wr;
    ACC8(A); ACC8(B); ACC8(C); ACC8(D);
    int i0 = n0*64;
    if (bf){
        const unsigned short* Wh = (const unsigned short*)Wsel;
        const unsigned short* xh = (const unsigned short*)x;
        for (int k = 0; k < 64; ++k){
            const unsigned short* w0 = Wh + k*64 + cc;
            const unsigned short* w1 = w0 + 64*64;
            float u0=bf2f(w0[0]),u1=bf2f(w0[1]),u2=bf2f(w0[2]),u3=bf2f(w0[3]),
                  u4=bf2f(w0[4]),u5=bf2f(w0[5]),u6=bf2f(w0[6]),u7=bf2f(w0[7]);
            float v0=bf2f(w1[0]),v1=bf2f(w1[1]),v2=bf2f(w1[2]),v3=bf2f(w1[3]),
                  v4=bf2f(w1[4]),v5=bf2f(w1[5]),v6=bf2f(w1[6]),v7=bf2f(w1[7]);
            float a, b;
            a = g0?bf2f(xh[i0+k]):0.f;     b = g0?rs[i0+k]:0.f;     FMA8(A,a,b);
            a = g1?bf2f(xh[i0+64+k]):0.f;  b = g1?rs[i0+64+k]:0.f;  FMA8(B,a,b);
            a = g2?bf2f(xh[i0+128+k]):0.f; b = g2?rs[i0+128+k]:0.f; FMA8(C,a,b);
            a = g3?bf2f(xh[i0+192+k]):0.f; b = g3?rs[i0+192+k]:0.f; FMA8(D,a,b);
        }
    } else {
        const float* Wf = (const float*)Wsel;
        const float* xf = (const float*)x;
        for (int k = 0; k < 64; ++k){
            const float* w0 = Wf + k*64 + cc;
            const float* w1 = w0 + 64*64;
            float u0=w0[0],u1=w0[1],u2=w0[2],u3=w0[3],u4=w0[4],u5=w0[5],u6=w0[6],u7=w0[7];
            float v0=w1[0],v1=w1[1],v2=w1[2],v3=w1[3],v4=w1[4],v5=w1[5],v6=w1[6],v7=w1[7];
            float a, b;
            a = g0?xf[i0+k]:0.f;     b = g0?rs[i0+k]:0.f;     FMA8(A,a,b);
            a = g1?xf[i0+64+k]:0.f;  b = g1?rs[i0+64+k]:0.f;  FMA8(B,a,b);
            a = g2?xf[i0+128+k]:0.f; b = g2?rs[i0+128+k]:0.f; FMA8(C,a,b);
            a = g3?xf[i0+192+k]:0.f; b = g3?rs[i0+192+k]:0.f; FMA8(D,a,b);
        }
    }
    if (g0){ unsigned short* o = X1b + n0*128 + c0;       STORE8(A,o); }
    if (g1){ unsigned short* o = X1b + (n0+1)*128 + c0;   STORE8(B,o); }
    if (g2){ unsigned short* o = X1b + (n0+2)*128 + c0;   STORE8(C,o); }
    if (g3){ unsigned short* o = X1b + (n0+3)*128 + c0;   STORE8(D,o); }
}

// edge gather: bf16 X1 in, bf16 m out (packed u32 pair store). 32 threads/edge.
__global__ void k_gather_e2(const int* indptr_e, const int* Bc, const int* elist,
                            const unsigned short* X1b, const void* hw,
                            const float* Binv, unsigned* mb, int pairBase, int CP,
                            const int* flag){
    int bf = *flag;
    int t = blockIdx.x*256 + threadIdx.x;
    if (t >= N_EDGES*32) return;
    int e = t >> 5, p = t & 31;
    int cp = pairBase + p;
    int beg = indptr_e[e], cnt = Bc[e];
    float acc0 = 0.f, acc1 = 0.f;
    for (int j = 0; j < cnt; ++j){
        int n = elist[beg + j];
        unsigned v = *(const unsigned*)(X1b + n*128 + cp*2);
        acc0 += bf2f((unsigned short)(v & 0xFFFFu));
        acc1 += bf2f((unsigned short)(v >> 16));
    }
    float wsc = ldv(hw, e, bf) * Binv[e];
    unsigned lo = f2bf(acc0 * wsc);
    unsigned hi = f2bf(acc1 * wsc);
    mb[e*CP + cp] = lo | (hi << 16);     // CP = C/2 pairs per edge
}

// fused node gather + gate prep: thread per (node, 4-col group), m bf16, nlist u16.
__global__ void k_gather_prep_gate(const int* indptr_n, const int* Dc,
                                   const unsigned short* nlist, const unsigned* mb,
                                   const void* x, const void* st,
                                   const float* Dinv, const void* gb,
                                   float* P, const int* flag){
    int bf = *flag;
    int t = blockIdx.x*256 + threadIdx.x;
    if (t >= N_NODES*32) return;
    int n = t >> 5, g = t & 31;
    int c = g*4;
    int beg = indptr_n[n], cnt = Dc[n];
    float a0 = 0.f, a1 = 0.f, a2 = 0.f, a3 = 0.f;
    for (int j = 0; j < cnt; ++j){
        int e = nlist[beg + j];
        const unsigned* q = mb + e*64 + g*2;
        unsigned va = q[0], vb = q[1];
        a0 += bf2f((unsigned short)(va & 0xFFFFu));
        a1 += bf2f((unsigned short)(va >> 16));
        a2 += bf2f((unsigned short)(vb & 0xFFFFu));
        a3 += bf2f((unsigned short)(vb >> 16));
    }
    float di = Dinv[n];
    float b0, b1, b2, b3;
    if (c < 64){
        b0 = ldv(x, n*64 + c, bf);     b1 = ldv(x, n*64 + c + 1, bf);
        b2 = ldv(x, n*64 + c + 2, bf); b3 = ldv(x, n*64 + c + 3, bf);
    } else {
        int cc = c - 64;
        b0 = ldv(st, n*64 + cc, bf);     b1 = ldv(st, n*64 + cc + 1, bf);
        b2 = ldv(st, n*64 + cc + 2, bf); b3 = ldv(st, n*64 + cc + 3, bf);
    }
    float v0 = b0 + di*a0 + ldv(gb, c, bf);
    float v1 = b1 + di*a1 + ldv(gb, c + 1, bf);
    float v2 = b2 + di*a2 + ldv(gb, c + 2, bf);
    float v3 = b3 + di*a3 + ldv(gb, c + 3, bf);
    if (v0 < 0.f) v0 = 0.f;
    if (v1 < 0.f) v1 = 0.f;
    if (v2 < 0.f) v2 = 0.f;
    if (v3 < 0.f) v3 = 0.f;
    float* o = P + n*128 + c;
    o[0] = v0; o[1] = v1; o[2] = v2; o[3] = v3;
}

// fused node gather + cand prep: thread per (node, 4-col group), m bf16 (CP=32), nlist u16.
__global__ void k_gather_prep_cand(const int* indptr_n, const int* Dc,
                                   const unsigned short* nlist, const unsigned* mb,
                                   const unsigned short* X1b, const float* Dinv,
                                   const void* cbv, const void* crb,
                                   float* P2, const int* flag){
    int bf = *flag;
    int t = blockIdx.x*256 + threadIdx.x;
    if (t >= N_NODES*16) return;
    int n = t >> 4, g = t & 15;
    int c = g*4;
    int beg = indptr_n[n], cnt = Dc[n];
    float a0 = 0.f, a1 = 0.f, a2 = 0.f, a3 = 0.f;
    for (int j = 0; j < cnt; ++j){
        int e = nlist[beg + j];
        const unsigned* q = mb + e*32 + g*2;
        unsigned va = q[0], vb = q[1];
        a0 += bf2f((unsigned short)(va & 0xFFFFu));
        a1 += bf2f((unsigned short)(va >> 16));
        a2 += bf2f((unsigned short)(vb & 0xFFFFu));
        a3 += bf2f((unsigned short)(vb >> 16));
    }
    float di = Dinv[n];
    float v0 = bf2f(X1b[n*128 + 64 + c])     + ldv(crb, c, bf)     + di*a0 + ldv(cbv, c, bf);
    float v1 = bf2f(X1b[n*128 + 64 + c + 1]) + ldv(crb, c + 1, bf) + di*a1 + ldv(cbv, c + 1, bf);
    float v2 = bf2f(X1b[n*128 + 64 + c + 2]) + ldv(crb, c + 2, bf) + di*a2 + ldv(cbv, c + 2, bf);
    float v3 = bf2f(X1b[n*128 + 64 + c + 3]) + ldv(crb, c + 3, bf) + di*a3 + ldv(cbv, c + 3, bf);
    if (v0 < 0.f) v0 = 0.f;
    if (v1 < 0.f) v1 = 0.f;
    if (v2 < 0.f) v2 = 0.f;
    if (v3 < 0.f) v3 = 0.f;
    float* o = P2 + n*64 + c;
    o[0] = v0; o[1] = v1; o[2] = v2; o[3] = v3;
}

// row stats: thread per node, 64-thread blocks (block footprint fits L1).
__global__ void k_stat(const float* P, float* pstat, int nrows, int C){
    int n = blockIdx.x*64 + threadIdx.x;
    if (n >= nrows) return;
    float s = 0.f, sq = 0.f;
    for (int c = 0; c < C; ++c){
        float v = P[n*C + c];
        s += v; sq += v*v;
    }
    pstat[n*2]     = s;
    pstat[n*2 + 1] = sq;
}

// gate fin: thread per (node, col<64).
__global__ void k_gate_fin2(const void* st, const float* P, const float* pstat,
                            const void* lng, const void* lnb,
                            float* zbuf, float* rs, const int* flag){
    int bf = *flag;
    int t = blockIdx.x*256 + threadIdx.x;
    if (t >= N_NODES*64) return;
    int n = t >> 6, c = t & 63;
    float s  = pstat[2*n];
    float sq = pstat[2*n + 1];
    float mu = s * (1.f/128.f);
    float var = sq * (1.f/128.f) - mu*mu;
    if (var < 0.f) var = 0.f;
    float inv = 1.f / sqrtf(var + 1e-5f);
    float v0 = P[n*128 + c];
    float v1 = P[n*128 + 64 + c];
    float u0 = (v0 - mu)*inv*ldv(lng, c, bf)      + ldv(lnb, c, bf);
    float u1 = (v1 - mu)*inv*ldv(lng, 64 + c, bf) + ldv(lnb, 64 + c, bf);
    float z = 1.f/(1.f + expf(-u0));
    float r = 1.f/(1.f + expf(-u1));
    float s1 = ldv(st, t, bf);
    zbuf[t] = z;
    rs[t]   = r * s1;
}

// cand fin: thread per (node, col). LN + tanh + GRU blend -> out.
__global__ void k_cand_fin2(const void* st, const float* P2, const float* pstat,
                            const void* lng, const void* lnb, const float* zbuf,
                            void* out, const int* flag){
    int bf = *flag;
    int t = blockIdx.x*256 + threadIdx.x;
    if (t >= N_NODES*64) return;
    int n = t >> 6, c = t & 63;
    float s  = pstat[2*n];
    float sq = pstat[2*n + 1];
    float mu = s * (1.f/64.f);
    float var = sq * (1.f/64.f) - mu*mu;
    if (var < 0.f) var = 0.f;
    float inv = 1.f / sqrtf(var + 1e-5f);
    float v = P2[t];
    float u = (v - mu)*inv*ldv(lng, c, bf) + ldv(lnb, c, bf);
    float hc = tanhf(u);
    float z = zbuf[t];
    float sv = ldv(st, t, bf);
    float res = (1.f - z)*sv + z*hc;
    if (bf) ((unsigned short*)out)[t] = f2bf(res);
    else    ((float*)out)[t] = res;
}

extern "C" void kernel_launch(void* const* d_in, const int* in_sizes, int n_in,
                              void* d_out, int out_size, void* d_ws, size_t ws_size,
                              hipStream_t stream){
    const void* x      = d_in[0];
    const void* state  = d_in[1];
    const int*  hidx   = (const int*)d_in[2];
    const void* hw     = d_in[3];
    const void* gate_W = d_in[4];
    const void* gate_b = d_in[5];
    const void* glng   = d_in[6];
    const void* glnb   = d_in[7];
    const void* cand_W = d_in[8];
    const void* cand_b = d_in[9];
    const void* clng   = d_in[10];
    const void* clnb   = d_in[11];
    const void* crW    = d_in[12];
    const void* crb    = d_in[13];
    (void)in_sizes; (void)n_in; (void)ws_size; (void)out_size;

    const int* nidx = hidx;
    const int* eidx = hidx + N_INC;

    const int NCH_N = (N_NODES + 127)/128;   // 391
    const int NCH_E = (N_EDGES + 127)/128;   // 79

    // ---- workspace (byte offsets, 256B-aligned, total ~73.5 MB) ----
    char* w = (char*)d_ws;
    int*   flag     = (int*)  (w);
    float* Dinv     = (float*)(w + 256);        // 50048 f (computed by k_dinv)
    int*   Bc       = (int*)  (w + 200448);     // 10048 i  (Bc,Dc contiguous: zeroed)
    int*   Dc       = (int*)  (w + 240640);     // 50048 i
    float* Binv     = (float*)(w + 440832);     // 10048 f
    int*   indptr_n = (int*)  (w + 481024);     // 50048 i
    int*   cursor_n = (int*)  (w + 681216);     // 50048 i
    int*   indptr_e = (int*)  (w + 881408);     // 10048 i
    int*   cursor_e = (int*)  (w + 921600);     // 10048 i
    int*   csum_n   = (int*)  (w + 961792);     // 512 i
    int*   cbase_n  = (int*)  (w + 963840);     // 512 i
    int*   csum_e   = (int*)  (w + 965888);     // 256 i
    int*   cbase_e  = (int*)  (w + 966912);     // 256 i
    unsigned short* nlist = (unsigned short*)(w + 967936);  // 800000 u16
    int*   elist    = (int*)  (w + 2567936);    // 800000 i
    unsigned* mb    = (unsigned*)(w + 5767936); // 10000*64 u32 (=128 bf16 cols)
    unsigned short* X1b = (unsigned short*)(w + 8327936);   // 50000*128 u16
    float* P        = (float*)(w + 21127936);   // 50000*128 f (gate P; cand P2 aliases)
    float* P2       = P;
    float* zbuf     = (float*)(w + 46727936);   // 50000*64 f
    float* rs       = (float*)(w + 59527936);   // 50000*64 f
    float* pstat_g  = (float*)(w + 72327936);   // 100000 f
    float* pstat_c  = (float*)(w + 73127936);   // 100000 f -> ends 73527936

    // dtype detect
    k_detect<<<1, 64, 0, stream>>>((const unsigned short*)hw, flag);

    // zero Bc,Dc (contiguous 60096 words)
    k_zero<<<(60096 + 255)/256, 256, 0, stream>>>((float*)(w + 200448), 60096);

    // degrees + CSR build
    k_count<<<(N_INC + 255)/256, 256, 0, stream>>>(nidx, eidx, Dc, Bc);
    k_binv<<<(N_EDGES + 255)/256, 256, 0, stream>>>(Bc, Binv);
    k_chunksum<<<(NCH_N + 255)/256, 256, 0, stream>>>(Dc, csum_n, N_NODES, NCH_N);
    k_chunkscan<<<1, 64, 0, stream>>>(csum_n, cbase_n, NCH_N);
    k_chunkfill<<<(NCH_N + 255)/256, 256, 0, stream>>>(Dc, cbase_n, indptr_n, cursor_n,
                                                       N_NODES, NCH_N);
    k_chunksum<<<(NCH_E + 255)/256, 256, 0, stream>>>(Bc, csum_e, N_EDGES, NCH_E);
    k_chunkscan<<<1, 64, 0, stream>>>(csum_e, cbase_e, NCH_E);
    k_chunkfill<<<(NCH_E + 255)/256, 256, 0, stream>>>(Bc, cbase_e, indptr_e, cursor_e,
                                                       N_EDGES, NCH_E);
    k_fill<<<(N_INC + 255)/256, 256, 0, stream>>>(nidx, eidx, cursor_n, nlist,
                                                  cursor_e, elist);
    k_dinv<<<(N_NODES + 255)/256, 256, 0, stream>>>(indptr_n, Dc, nlist, hw, Dinv, flag);

    // ---- gate path ----
    k_gemm_gate<<<(N_NODES + 63)/64, 256, 0, stream>>>(x, state, gate_W, X1b, flag);
    k_gather_e2<<<(N_EDGES*32 + 255)/256, 256, 0, stream>>>(indptr_e, Bc, elist, X1b,
                                                            hw, Binv, mb, 0, 64, flag);
    k_gather_e2<<<(N_EDGES*32 + 255)/256, 256, 0, stream>>>(indptr_e, Bc, elist, X1b,
                                                            hw, Binv, mb, 32, 64, flag);
    k_gather_prep_gate<<<(N_NODES*32 + 255)/256, 256, 0, stream>>>(indptr_n, Dc, nlist,
                                                                   mb, x, state, Dinv,
                                                                   gate_b, P, flag);
    k_stat<<<(N_NODES + 63)/64, 64, 0, stream>>>(P, pstat_g, N_NODES, 128);
    k_gate_fin2<<<(N_NODES*64 + 255)/256, 256, 0, stream>>>(state, P, pstat_g,
                                                            glng, glnb, zbuf, rs, flag);

    // ---- candidate path ----
    k_gemm_cand<<<(N_NODES + 63)/64, 256, 0, stream>>>(x, rs, cand_W, crW, X1b, flag);
    k_gather_e2<<<(N_EDGES*32 + 255)/256, 256, 0, stream>>>(indptr_e, Bc, elist, X1b,
                                                            hw, Binv, mb, 0, 32, flag);
    k_gather_prep_cand<<<(N_NODES*16 + 255)/256, 256, 0, stream>>>(indptr_n, Dc, nlist,
                                                                   mb, X1b, Dinv, cand_b,
                                                                   crb, P2, flag);
    k_stat<<<(N_NODES + 63)/64, 64, 0, stream>>>(P2, pstat_c, N_NODES, 64);
    k_cand_fin2<<<(N_NODES*64 + 255)/256, 256, 0, stream>>>(state, P2, pstat_c,
                                                            clng, clnb, zbuf,
                                                            d_out, flag);
}